// Round 14
// baseline (2476.315 us; speedup 1.0000x reference)
//
#include <hip/hip_runtime.h>
#include <math.h>

#define DIM    512
#define KCB    8192
#define NROWS  32768

typedef _Float16 f16x8 __attribute__((ext_vector_type(8)));
typedef float    f32x4 __attribute__((ext_vector_type(4)));

// ---- workspace layout (main path) ----
#define OFF_ZH    0ull                    // f16 Z  [32768][512] = 33554432 B
#define OFF_EH    33554432ull             // f16 E*8192 [8192][512] = 8388608 B
#define OFF_EE    41943040ull             // f32 ee [8192]
#define OFF_ZZ    41975808ull             // f32 zz [32768]
#define OFF_CNT   42106880ull             // u32 cnt[32768]
#define OFF_LOSS  42237952ull             // f64 loss accumulator
#define OFF_CAND  42237960ull             // u32 cand[32768][cap] (packed score|idx)
// rowmax u32[32768] follows cand; sizes:
#define WS_NEEDED_64  50757640ull         // cap = 64  (cand 8 MB + rowmax 128 KB)
#define WS_NEEDED_128 59146248ull         // cap = 128 (cand 16 MB + rowmax 128 KB)
// screen keeps k if dot16_scaled >= curmax - THR (E scaled by 2^13; folds ee
// and all f16 error into the margin; r3/r5/r6/r7/r10/r11/r12-proven). curmax
// = max(shared per-row atomicMax value, local wave max) — any value <= true
// global max16 only loosens the threshold, correctness unchanged.
#define THR 2.048f
// candidate entry: high 19 bits = float bits of (score+512) with low 13
// mantissa bits zeroed (quant err <= 0.5; clamped positive -> bit-monotone);
// low 13 bits = k. finish prunes at (global best - 2.6): winner needs
// 0.98 (proven slack) + 0.5 (quant) = 1.48 -> 2.6 safe. [r11/r12-proven]
#define SCORE_OFS 512.0f
#define PRUNE_MARGIN 2.6f

__device__ __forceinline__ void gl_lds16(const void* g, void* l) {
    __builtin_amdgcn_global_load_lds(
        (const __attribute__((address_space(1))) unsigned int*)g,
        (__attribute__((address_space(3))) unsigned int*)l, 16, 0, 0);
}

// ---------------------------------------------------------------------------
// prep2: fused norms + f16 conversion, one pass over Z and E (r13-proven).
// 4 lanes/row; lane b handles the b-th 128-elem block: bit-identical blk128
// chain + f16 convert/store of the same loaded values. Exact ((b0+b1)+(b2+b3))
// combine via shfl_xor (shuffles don't round; add order = r1-proven chain).
// ---------------------------------------------------------------------------
__device__ __forceinline__ float blk128_sq_cvt(const float* __restrict__ p,
                                               _Float16* __restrict__ o, float scale) {
    const float4* a4 = (const float4*)p;
    float4 v0 = a4[0], v1 = a4[1];
    float r[8];
    r[0] = __fmul_rn(v0.x, v0.x); r[1] = __fmul_rn(v0.y, v0.y);
    r[2] = __fmul_rn(v0.z, v0.z); r[3] = __fmul_rn(v0.w, v0.w);
    r[4] = __fmul_rn(v1.x, v1.x); r[5] = __fmul_rn(v1.y, v1.y);
    r[6] = __fmul_rn(v1.z, v1.z); r[7] = __fmul_rn(v1.w, v1.w);
    {
        f16x8 h;
        h[0] = (_Float16)(v0.x * scale); h[1] = (_Float16)(v0.y * scale);
        h[2] = (_Float16)(v0.z * scale); h[3] = (_Float16)(v0.w * scale);
        h[4] = (_Float16)(v1.x * scale); h[5] = (_Float16)(v1.y * scale);
        h[6] = (_Float16)(v1.z * scale); h[7] = (_Float16)(v1.w * scale);
        *(f16x8*)o = h;
    }
#pragma unroll
    for (int i = 1; i < 16; ++i) {
        v0 = a4[i * 2]; v1 = a4[i * 2 + 1];
        r[0] = __fadd_rn(r[0], __fmul_rn(v0.x, v0.x));
        r[1] = __fadd_rn(r[1], __fmul_rn(v0.y, v0.y));
        r[2] = __fadd_rn(r[2], __fmul_rn(v0.z, v0.z));
        r[3] = __fadd_rn(r[3], __fmul_rn(v0.w, v0.w));
        r[4] = __fadd_rn(r[4], __fmul_rn(v1.x, v1.x));
        r[5] = __fadd_rn(r[5], __fmul_rn(v1.y, v1.y));
        r[6] = __fadd_rn(r[6], __fmul_rn(v1.z, v1.z));
        r[7] = __fadd_rn(r[7], __fmul_rn(v1.w, v1.w));
        f16x8 h;
        h[0] = (_Float16)(v0.x * scale); h[1] = (_Float16)(v0.y * scale);
        h[2] = (_Float16)(v0.z * scale); h[3] = (_Float16)(v0.w * scale);
        h[4] = (_Float16)(v1.x * scale); h[5] = (_Float16)(v1.y * scale);
        h[6] = (_Float16)(v1.z * scale); h[7] = (_Float16)(v1.w * scale);
        *(f16x8*)(o + i * 8) = h;
    }
    return __fadd_rn(__fadd_rn(__fadd_rn(r[0], r[1]), __fadd_rn(r[2], r[3])),
                     __fadd_rn(__fadd_rn(r[4], r[5]), __fadd_rn(r[6], r[7])));
}

__global__ __launch_bounds__(256)
void prep2_kernel(const float* __restrict__ Z, const float* __restrict__ E,
                  _Float16* __restrict__ Zh, _Float16* __restrict__ Eh,
                  float* __restrict__ zz, float* __restrict__ ee,
                  unsigned int* __restrict__ cnt, unsigned int* __restrict__ rowmax,
                  double* __restrict__ lossAcc) {
    const int id = blockIdx.x * 256 + threadIdx.x;   // (NROWS+KCB)*4 total
    const int row = id >> 2, b = id & 3;
    if (id == 0) *lossAcc = 0.0;
    float blk;
    if (row < NROWS) {
        blk = blk128_sq_cvt(Z + (size_t)row * DIM + b * 128,
                            Zh + (size_t)row * DIM + b * 128, 1.0f);
    } else {
        const int k = row - NROWS;
        blk = blk128_sq_cvt(E + (size_t)k * DIM + b * 128,
                            Eh + (size_t)k * DIM + b * 128, 8192.0f);
    }
    float v1 = __fadd_rn(blk, __shfl_xor(blk, 1, 64));
    float v2 = __fadd_rn(v1, __shfl_xor(v1, 2, 64));
    if (b == 0) {
        if (row < NROWS) { zz[row] = v2; cnt[row] = 0; rowmax[row] = 0u; }
        else             ee[row - NROWS] = v2;
    }
}

// ---------------------------------------------------------------------------
// Screen v14 — r12 body VERBATIM (501 µs proven: 128x128 tile, BK=32,
// 4 waves, 16 KiB single-buffered LDS, plain __syncthreads, m97 K-loop,
// shared per-row atomicMax threshold, grid 16384 colTile-major).
// ONE change: __launch_bounds__(256,6) — r12's binding limit was the
// (256,4) cap itself (40.5% occupancy, VGPR 64 used vs 128 cap, LDS 16K
// allows 10 blocks). 6 waves/EU -> 6 blocks/CU target (96 KiB LDS), VGPR
// cap 85 with 64 used (margin; r13's cap-102 spill came from the two-half
// frag set, removed here). More resident blocks = more inter-block slip
// (r10->r12: 17%->24% MfmaUtil as blocks/CU rose).
// ---------------------------------------------------------------------------
__global__ __launch_bounds__(256, 6)
void screen_kernel(const _Float16* __restrict__ Zh, const _Float16* __restrict__ Eh,
                   unsigned int* __restrict__ cnt, unsigned int* __restrict__ cand,
                   unsigned int* __restrict__ rowmax, const int cap) {
    __shared__ __align__(16) char lds[16384];   // A 8 KiB + B 8 KiB

    const int tid = threadIdx.x;
    const int l = tid & 63;
    const int w = tid >> 6;           // wave 0..3
    const int wrow = w >> 1;          // 0..1
    const int wcol = w & 1;           // 0..1
    const int rowBase = (int)(blockIdx.x & 255) * 128;
    const int colBase = (int)(blockIdx.x >> 8) * 128;

    // per-thread staging constants: units u = tid + i*256, i in {0,1}
    // A: row = u>>2, pos = u&3, swizzled src slot = pos ^ ((row>>1)&3)
#define STAGE(ks) do {                                                         \
        _Pragma("unroll")                                                      \
        for (int _i = 0; _i < 2; ++_i) {                                       \
            const int _u = tid + _i * 256;                                     \
            const int _r = _u >> 2;                                            \
            const int _s = (_u & 3) ^ ((_r >> 1) & 3);                         \
            gl_lds16(Zh + (size_t)(rowBase + _r) * DIM + (ks) * 32 + _s * 8,   \
                     lds + (w * 64 + _i * 256) * 16 + l * 16);                 \
            gl_lds16(Eh + (size_t)(colBase + _r) * DIM + (ks) * 32 + _s * 8,   \
                     lds + 8192 + (w * 64 + _i * 256) * 16 + l * 16);          \
        }                                                                      \
    } while (0)

    // frag byte offsets (step-invariant; r6/r12 algebra, 0-conflict)
    int offA[4], offB[4];
#pragma unroll
    for (int m = 0; m < 4; ++m) {
        const int rr = wrow * 64 + m * 16 + (l & 15);
        offA[m] = (rr * 4 + ((l >> 4) ^ ((rr >> 1) & 3))) * 16;
    }
#pragma unroll
    for (int n = 0; n < 4; ++n) {
        const int c = wcol * 64 + n * 16 + (l & 15);
        offB[n] = 8192 + (c * 4 + ((l >> 4) ^ ((c >> 1) & 3))) * 16;
    }

    f32x4 acc[4][4];
#pragma unroll
    for (int m = 0; m < 4; ++m)
#pragma unroll
        for (int n = 0; n < 4; ++n) acc[m][n] = (f32x4){0.f, 0.f, 0.f, 0.f};

    // m97 K-loop: stage -> sync (vmcnt drain) -> read+MFMA -> sync
    for (int ks = 0; ks < 16; ++ks) {
        STAGE(ks);
        __syncthreads();
        f16x8 af[4], bf[4];
#pragma unroll
        for (int m = 0; m < 4; ++m) af[m] = *(const f16x8*)(lds + offA[m]);
#pragma unroll
        for (int n = 0; n < 4; ++n) bf[n] = *(const f16x8*)(lds + offB[n]);
#pragma unroll
        for (int m = 0; m < 4; ++m)
#pragma unroll
            for (int n = 0; n < 4; ++n)
                acc[m][n] = __builtin_amdgcn_mfma_f32_16x16x32_f16(af[m], bf[n], acc[m][n], 0, 0, 0);
        if (ks < 15) __syncthreads();
    }

    // epilogue: shared-rowmax screen + packed append (r12 verbatim)
#pragma unroll
    for (int m = 0; m < 4; ++m) {
#pragma unroll
        for (int r = 0; r < 4; ++r) {
            float mx = fmaxf(fmaxf(acc[m][0][r], acc[m][1][r]),
                             fmaxf(acc[m][2][r], acc[m][3][r]));
#pragma unroll
            for (int off = 1; off < 16; off <<= 1)
                mx = fmaxf(mx, __shfl_xor(mx, off, 64));
            const int rowg = rowBase + wrow * 64 + m * 16 + (l >> 4) * 4 + r;
            const float mxs = fmaxf(mx, -256.0f) + SCORE_OFS;   // positive
            unsigned old = 0;
            if ((l & 15) == 0)
                old = atomicMax(&rowmax[rowg], __float_as_uint(mxs));
            old = __shfl(old, l & 48, 64);   // broadcast group leader's old
            const float cur = fmaxf(__uint_as_float(old), mxs);
            const float thr = cur - SCORE_OFS - THR;
#pragma unroll
            for (int n = 0; n < 4; ++n) {
                if (acc[m][n][r] >= thr) {
                    unsigned pos = atomicAdd(&cnt[rowg], 1u);
                    if (pos < (unsigned)cap) {
                        unsigned kidx = (unsigned)(colBase + wcol * 64 + n * 16 + (l & 15));
                        float sc = fmaxf(acc[m][n][r] + SCORE_OFS, 1.0f);
                        cand[(size_t)rowg * cap + pos] =
                            (__float_as_uint(sc) & 0xFFFFE000u) | kidx;
                    }
                }
            }
        }
    }
#undef STAGE
}

// ---------------------------------------------------------------------------
// finish: prune via packed scores, exact rescore (bit-identical chain),
// gather + loss. c > cap or c == 0 -> exact full 8192-code scan.
// [r10/r11/r12-proven, verbatim]
// ---------------------------------------------------------------------------
__global__ __launch_bounds__(256)
void finish_kernel(const float* __restrict__ Z, const float* __restrict__ E,
                   const float* __restrict__ zz, const float* __restrict__ ee,
                   const unsigned int* __restrict__ cnt,
                   const unsigned int* __restrict__ cand,
                   float* __restrict__ outZ, float* __restrict__ outIdxF,
                   double* __restrict__ lossAcc, const int cap) {
    __shared__ double psum[4];
    const int tid = threadIdx.x;
    const int l = tid & 63;
    const int w = tid >> 6;
    double s = 0.0;

    for (int j = 0; j < 8; ++j) {
        const int row = blockIdx.x * 32 + w * 8 + j;
        const unsigned c = cnt[row];
        int kk;
        if (c == 1) {
            kk = (int)(cand[(size_t)row * cap] & 0x1FFFu);
        } else if (c >= 2 && c <= (unsigned)cap) {
            const unsigned key1 = (l < (int)c) ? cand[(size_t)row * cap + l] : 0u;
            const unsigned key2 = ((int)c > 64 && l + 64 < (int)c)
                                      ? cand[(size_t)row * cap + l + 64] : 0u;
            const float s1 = __uint_as_float(key1 & 0xFFFFE000u);
            const float s2 = __uint_as_float(key2 & 0xFFFFE000u);
            float smax = fmaxf(s1, s2);
#pragma unroll
            for (int off = 1; off < 64; off <<= 1)
                smax = fmaxf(smax, __shfl_xor(smax, off, 64));
            const float cut = smax - PRUNE_MARGIN;

            float d2 = __builtin_inff();
            int kl = 0x7FFFFFFF;
            const float4* zr4 = (const float4*)(Z + (size_t)row * DIM);
            if (l < (int)c && s1 >= cut) {
                int k = (int)(key1 & 0x1FFFu);
                const float4* er4 = (const float4*)(E + (size_t)k * DIM);
                float acc = 0.0f;
#pragma unroll 8
                for (int i = 0; i < DIM / 4; ++i) {
                    float4 z4 = zr4[i], e4 = er4[i];
                    acc = __builtin_fmaf(z4.x, e4.x, acc);
                    acc = __builtin_fmaf(z4.y, e4.y, acc);
                    acc = __builtin_fmaf(z4.z, e4.z, acc);
                    acc = __builtin_fmaf(z4.w, e4.w, acc);
                }
                float t = __builtin_fmaf(-2.0f, acc, zz[row]);
                d2 = __fadd_rn(t, ee[k]);
                kl = k;
            }
            if ((int)c > 64 && l + 64 < (int)c && s2 >= cut) {
                int k = (int)(key2 & 0x1FFFu);
                const float4* er4 = (const float4*)(E + (size_t)k * DIM);
                float acc = 0.0f;
#pragma unroll 8
                for (int i = 0; i < DIM / 4; ++i) {
                    float4 z4 = zr4[i], e4 = er4[i];
                    acc = __builtin_fmaf(z4.x, e4.x, acc);
                    acc = __builtin_fmaf(z4.y, e4.y, acc);
                    acc = __builtin_fmaf(z4.z, e4.z, acc);
                    acc = __builtin_fmaf(z4.w, e4.w, acc);
                }
                float t = __builtin_fmaf(-2.0f, acc, zz[row]);
                float d = __fadd_rn(t, ee[k]);
                if (d < d2 || (d == d2 && k < kl)) { d2 = d; kl = k; }
            }
#pragma unroll
            for (int off = 32; off > 0; off >>= 1) {
                float od = __shfl_down(d2, off, 64);
                int ok = __shfl_down(kl, off, 64);
                if (od < d2 || (od == d2 && ok < kl)) { d2 = od; kl = ok; }
            }
            kk = __shfl(kl, 0, 64);
        } else {
            // overflow (c > cap) or degenerate (c == 0): exact full scan
            float d2 = __builtin_inff();
            int kl = 0x7FFFFFFF;
            const float4* zr4 = (const float4*)(Z + (size_t)row * DIM);
            for (int k = l; k < KCB; k += 64) {
                const float4* er4 = (const float4*)(E + (size_t)k * DIM);
                float acc = 0.0f;
#pragma unroll 8
                for (int i = 0; i < DIM / 4; ++i) {
                    float4 z4 = zr4[i], e4 = er4[i];
                    acc = __builtin_fmaf(z4.x, e4.x, acc);
                    acc = __builtin_fmaf(z4.y, e4.y, acc);
                    acc = __builtin_fmaf(z4.z, e4.z, acc);
                    acc = __builtin_fmaf(z4.w, e4.w, acc);
                }
                float t = __builtin_fmaf(-2.0f, acc, zz[row]);
                float d = __fadd_rn(t, ee[k]);
                if (d < d2) { d2 = d; kl = k; }   // per-lane k ascending
            }
#pragma unroll
            for (int off = 32; off > 0; off >>= 1) {
                float od = __shfl_down(d2, off, 64);
                int ok = __shfl_down(kl, off, 64);
                if (od < d2 || (od == d2 && ok < kl)) { d2 = od; kl = ok; }
            }
            kk = __shfl(kl, 0, 64);
        }
        const float* zr = Z + (size_t)row * DIM;
        const float* er = E + (size_t)kk * DIM;
        float* orow = outZ + (size_t)row * DIM;
#pragma unroll
        for (int i = 0; i < 2; ++i) {
            int off = (l + i * 64) * 4;
            float4 z4 = *(const float4*)(zr + off);
            float4 e4 = *(const float4*)(er + off);
            float dx = __fsub_rn(e4.x, z4.x);
            float dy = __fsub_rn(e4.y, z4.y);
            float dz = __fsub_rn(e4.z, z4.z);
            float dw = __fsub_rn(e4.w, z4.w);
            float4 st;
            st.x = __fadd_rn(z4.x, dx);
            st.y = __fadd_rn(z4.y, dy);
            st.z = __fadd_rn(z4.z, dz);
            st.w = __fadd_rn(z4.w, dw);
            *(float4*)(orow + off) = st;
            s += (double)dx * dx + (double)dy * dy + (double)dz * dz + (double)dw * dw;
        }
        if (l == 0) outIdxF[row] = (float)kk;
    }
#pragma unroll
    for (int o = 32; o > 0; o >>= 1) s += __shfl_down(s, o, 64);
    if (l == 0) psum[w] = s;
    __syncthreads();
    if (tid == 0)
        atomicAdd(lossAcc, psum[0] + psum[1] + psum[2] + psum[3]);
}

__global__ void finalize_kernel(const double* __restrict__ lossAcc,
                                float* __restrict__ outLoss) {
    double m = *lossAcc / (double)((size_t)NROWS * DIM);
    float mf = (float)m;
    float c = __fmul_rn(0.25f, mf);
    *outLoss = __fadd_rn(c, mf);
}

// ---------------------------------------------------------------------------
// Fallback (ws too small): round-1 proven-correct VALU path, verbatim.
// ---------------------------------------------------------------------------
__device__ __forceinline__ float pairwise512_sq(const float* __restrict__ p) {
    float blk[4];
#pragma unroll
    for (int b = 0; b < 4; ++b) {
        const float* a = p + b * 128;
        float r[8];
#pragma unroll
        for (int j = 0; j < 8; ++j) r[j] = __fmul_rn(a[j], a[j]);
#pragma unroll
        for (int i = 8; i < 128; i += 8) {
#pragma unroll
            for (int j = 0; j < 8; ++j)
                r[j] = __fadd_rn(r[j], __fmul_rn(a[i + j], a[i + j]));
        }
        blk[b] = __fadd_rn(__fadd_rn(__fadd_rn(r[0], r[1]), __fadd_rn(r[2], r[3])),
                           __fadd_rn(__fadd_rn(r[4], r[5]), __fadd_rn(r[6], r[7])));
    }
    return __fadd_rn(__fadd_rn(blk[0], blk[1]), __fadd_rn(blk[2], blk[3]));
}

__global__ void ee_kernel(const float* __restrict__ E, float* __restrict__ ee) {
    int k = blockIdx.x * blockDim.x + threadIdx.x;
    if (k < KCB) ee[k] = pairwise512_sq(E + (size_t)k * DIM);
}

__global__ __launch_bounds__(512, 2)
void argmin_fallback(const float* __restrict__ Z, const float* __restrict__ E,
                     const float* __restrict__ ee, int* __restrict__ outIdx) {
    __shared__ __align__(16) char smem[(32 * 132 + 32 * 260) * 4];
    float (*As)[132] = (float (*)[132])smem;
    float (*Bs)[260] = (float (*)[260])(smem + 32 * 132 * 4);
    __shared__ float zzs[128];
    const int tid = threadIdx.x;
    const int tx = tid & 31;
    const int ty = tid >> 5;
    const int rowBase = blockIdx.x * 128;
    if (tid < 128) zzs[tid] = pairwise512_sq(Z + (size_t)(rowBase + tid) * DIM);
    __syncthreads();
    float zz[8];
#pragma unroll
    for (int m = 0; m < 8; ++m) zz[m] = zzs[ty * 8 + m];
    float bestV[8]; int bestI[8];
#pragma unroll
    for (int m = 0; m < 8; ++m) { bestV[m] = __builtin_inff(); bestI[m] = 0; }
    for (int tile = 0; tile < 32; ++tile) {
        float acc[8][8];
#pragma unroll
        for (int m = 0; m < 8; ++m)
#pragma unroll
            for (int n = 0; n < 8; ++n) acc[m][n] = 0.0f;
        for (int kc = 0; kc < DIM; kc += 32) {
            __syncthreads();
#pragma unroll
            for (int i = 0; i < 2; ++i) {
                int id4 = tid + i * 512;
                int r = id4 >> 3, c = id4 & 7;
                float4 v = *(const float4*)(Z + (size_t)(rowBase + r) * DIM + kc + c * 4);
                As[c * 4 + 0][r] = v.x; As[c * 4 + 1][r] = v.y;
                As[c * 4 + 2][r] = v.z; As[c * 4 + 3][r] = v.w;
            }
#pragma unroll
            for (int i = 0; i < 4; ++i) {
                int id4 = tid + i * 512;
                int r = id4 >> 3, c = id4 & 7;
                float4 v = *(const float4*)(E + (size_t)(tile * 256 + r) * DIM + kc + c * 4);
                Bs[c * 4 + 0][r] = v.x; Bs[c * 4 + 1][r] = v.y;
                Bs[c * 4 + 2][r] = v.z; Bs[c * 4 + 3][r] = v.w;
            }
            __syncthreads();
#pragma unroll
            for (int kk = 0; kk < 32; ++kk) {
                float a[8], b[8];
                *(float4*)&a[0] = *(const float4*)&As[kk][ty * 8];
                *(float4*)&a[4] = *(const float4*)&As[kk][ty * 8 + 4];
                *(float4*)&b[0] = *(const float4*)&Bs[kk][tx * 8];
                *(float4*)&b[4] = *(const float4*)&Bs[kk][tx * 8 + 4];
#pragma unroll
                for (int m = 0; m < 8; ++m)
#pragma unroll
                    for (int n = 0; n < 8; ++n)
                        acc[m][n] = __builtin_fmaf(a[m], b[n], acc[m][n]);
            }
        }
#pragma unroll
        for (int m = 0; m < 8; ++m) {
#pragma unroll
            for (int n = 0; n < 8; ++n) {
                float t = __builtin_fmaf(-2.0f, acc[m][n], zz[m]);
                float d2 = __fadd_rn(t, ee[tile * 256 + tx * 8 + n]);
                int kidx = tile * 256 + tx * 8 + n;
                if (d2 < bestV[m]) { bestV[m] = d2; bestI[m] = kidx; }
            }
        }
    }
    __syncthreads();
    float (*redV)[33] = (float (*)[33])smem;
    int   (*redI)[33] = (int (*)[33])(smem + 128 * 33 * 4);
#pragma unroll
    for (int m = 0; m < 8; ++m) {
        redV[ty * 8 + m][tx] = bestV[m];
        redI[ty * 8 + m][tx] = bestI[m];
    }
    __syncthreads();
    if (tid < 128) {
        float bv = redV[tid][0]; int bi = redI[tid][0];
        for (int j = 1; j < 32; ++j) {
            float v = redV[tid][j]; int ii = redI[tid][j];
            if (v < bv || (v == bv && ii < bi)) { bv = v; bi = ii; }
        }
        outIdx[rowBase + tid] = bi;
    }
}

__global__ void gather_kernel(const float* __restrict__ Z, const float* __restrict__ E,
                              const int* __restrict__ idx, float* __restrict__ outZ,
                              float* __restrict__ outIdxF, double* __restrict__ lossAcc) {
    int row = blockIdx.x;
    int t = threadIdx.x;  // 64
    int k = idx[row];
    const float* zr = Z + (size_t)row * DIM;
    const float* er = E + (size_t)k * DIM;
    float* orow = outZ + (size_t)row * DIM;
    double s = 0.0;
#pragma unroll
    for (int i = 0; i < 2; ++i) {
        int off = (t + i * 64) * 4;
        float4 z4 = *(const float4*)(zr + off);
        float4 e4 = *(const float4*)(er + off);
        float dx = __fsub_rn(e4.x, z4.x);
        float dy = __fsub_rn(e4.y, z4.y);
        float dz = __fsub_rn(e4.z, z4.z);
        float dw = __fsub_rn(e4.w, z4.w);
        float4 st;
        st.x = __fadd_rn(z4.x, dx);
        st.y = __fadd_rn(z4.y, dy);
        st.z = __fadd_rn(z4.z, dz);
        st.w = __fadd_rn(z4.w, dw);
        *(float4*)(orow + off) = st;
        s += (double)dx * dx + (double)dy * dy + (double)dz * dz + (double)dw * dw;
    }
#pragma unroll
    for (int o = 32; o > 0; o >>= 1) s += __shfl_down(s, o, 64);
    if (t == 0) {
        atomicAdd(lossAcc, s);
        outIdxF[row] = (float)k;
    }
}

// ---------------------------------------------------------------------------
extern "C" void kernel_launch(void* const* d_in, const int* in_sizes, int n_in,
                              void* d_out, int out_size, void* d_ws, size_t ws_size,
                              hipStream_t stream) {
    const float* Z = (const float*)d_in[0];
    const float* E = (const float*)d_in[1];
    float* out = (float*)d_out;
    float* zq_out = out;
    float* loss_out = out + (size_t)NROWS * DIM;
    float* idxf_out = loss_out + 1;

    if (ws_size >= WS_NEEDED_64) {
        const int cap = (ws_size >= WS_NEEDED_128) ? 128 : 64;
        _Float16* Zh = (_Float16*)((char*)d_ws + OFF_ZH);
        _Float16* Eh = (_Float16*)((char*)d_ws + OFF_EH);
        float* ee = (float*)((char*)d_ws + OFF_EE);
        float* zz = (float*)((char*)d_ws + OFF_ZZ);
        unsigned int* cnt = (unsigned int*)((char*)d_ws + OFF_CNT);
        unsigned int* cand = (unsigned int*)((char*)d_ws + OFF_CAND);
        unsigned int* rowmax = (unsigned int*)((char*)d_ws + OFF_CAND
                                               + (size_t)NROWS * cap * 4);
        double* lossAcc = (double*)((char*)d_ws + OFF_LOSS);

        prep2_kernel<<<(NROWS + KCB) * 4 / 256, 256, 0, stream>>>(Z, E, Zh, Eh, zz, ee,
                                                                  cnt, rowmax, lossAcc);
        screen_kernel<<<256 * 64, 256, 0, stream>>>(Zh, Eh, cnt, cand, rowmax, cap);
        finish_kernel<<<NROWS / 32, 256, 0, stream>>>(Z, E, zz, ee, cnt, cand,
                                                      zq_out, idxf_out, lossAcc, cap);
        finalize_kernel<<<1, 1, 0, stream>>>(lossAcc, loss_out);
    } else {
        float* ee = (float*)d_ws;
        int* idx = (int*)((char*)d_ws + 32768);
        double* lossAcc = (double*)((char*)d_ws + 163840);
        hipMemsetAsync(lossAcc, 0, sizeof(double), stream);
        ee_kernel<<<KCB / 256, 256, 0, stream>>>(E, ee);
        argmin_fallback<<<NROWS / 128, 512, 0, stream>>>(Z, E, ee, idx);
        gather_kernel<<<NROWS, 64, 0, stream>>>(Z, E, idx, zq_out, idxf_out, lossAcc);
        finalize_kernel<<<1, 1, 0, stream>>>(lossAcc, loss_out);
    }
}

// Round 15
// 2467.962 us; speedup vs baseline: 1.0034x; 1.0034x over previous
//
#include <hip/hip_runtime.h>
#include <math.h>

#define DIM    512
#define KCB    8192
#define NROWS  32768

typedef _Float16 f16x8 __attribute__((ext_vector_type(8)));
typedef float    f32x4 __attribute__((ext_vector_type(4)));

// ---- workspace layout (main path) ----
#define OFF_ZH    0ull                    // f16 Z  [32768][512] = 33554432 B
#define OFF_EH    33554432ull             // f16 E*8192 [8192][512] = 8388608 B
#define OFF_EE    41943040ull             // f32 ee [8192]
#define OFF_ZZ    41975808ull             // f32 zz [32768]
#define OFF_CNT   42106880ull             // u32 cnt[32768]
#define OFF_LOSS  42237952ull             // f64 loss accumulator
#define OFF_CAND  42237960ull             // u32 cand[32768][cap] (packed score|idx)
// rowmax u32[32768] follows cand; sizes:
#define WS_NEEDED_64  50757640ull         // cap = 64  (cand 8 MB + rowmax 128 KB)
#define WS_NEEDED_128 59146248ull         // cap = 128 (cand 16 MB + rowmax 128 KB)
// screen keeps k if dot16_scaled >= curmax - THR (E scaled by 2^13; folds ee
// and all f16 error into the margin; r3/r5/r6/r7/r10/r11/r12-proven). curmax
// = max(shared per-row atomicMax value, local wave max) — any value <= true
// global max16 only loosens the threshold, correctness unchanged.
#define THR 2.048f
// candidate entry: high 19 bits = float bits of (score+512) with low 13
// mantissa bits zeroed (quant err <= 0.5; clamped positive -> bit-monotone);
// low 13 bits = k. finish prunes at (global best - 2.6): winner needs
// 0.98 (proven slack) + 0.5 (quant) = 1.48 -> 2.6 safe. [r11/r12-proven]
#define SCORE_OFS 512.0f
#define PRUNE_MARGIN 2.6f

__device__ __forceinline__ void gl_lds16(const void* g, void* l) {
    __builtin_amdgcn_global_load_lds(
        (const __attribute__((address_space(1))) unsigned int*)g,
        (__attribute__((address_space(3))) unsigned int*)l, 16, 0, 0);
}

// ---------------------------------------------------------------------------
// prep2: fused norms + f16 conversion, one pass over Z and E (r13-proven).
// 4 lanes/row; lane b handles the b-th 128-elem block: bit-identical blk128
// chain + f16 convert/store of the same loaded values. Exact ((b0+b1)+(b2+b3))
// combine via shfl_xor (shuffles don't round; add order = r1-proven chain).
// ---------------------------------------------------------------------------
__device__ __forceinline__ float blk128_sq_cvt(const float* __restrict__ p,
                                               _Float16* __restrict__ o, float scale) {
    const float4* a4 = (const float4*)p;
    float4 v0 = a4[0], v1 = a4[1];
    float r[8];
    r[0] = __fmul_rn(v0.x, v0.x); r[1] = __fmul_rn(v0.y, v0.y);
    r[2] = __fmul_rn(v0.z, v0.z); r[3] = __fmul_rn(v0.w, v0.w);
    r[4] = __fmul_rn(v1.x, v1.x); r[5] = __fmul_rn(v1.y, v1.y);
    r[6] = __fmul_rn(v1.z, v1.z); r[7] = __fmul_rn(v1.w, v1.w);
    {
        f16x8 h;
        h[0] = (_Float16)(v0.x * scale); h[1] = (_Float16)(v0.y * scale);
        h[2] = (_Float16)(v0.z * scale); h[3] = (_Float16)(v0.w * scale);
        h[4] = (_Float16)(v1.x * scale); h[5] = (_Float16)(v1.y * scale);
        h[6] = (_Float16)(v1.z * scale); h[7] = (_Float16)(v1.w * scale);
        *(f16x8*)o = h;
    }
#pragma unroll
    for (int i = 1; i < 16; ++i) {
        v0 = a4[i * 2]; v1 = a4[i * 2 + 1];
        r[0] = __fadd_rn(r[0], __fmul_rn(v0.x, v0.x));
        r[1] = __fadd_rn(r[1], __fmul_rn(v0.y, v0.y));
        r[2] = __fadd_rn(r[2], __fmul_rn(v0.z, v0.z));
        r[3] = __fadd_rn(r[3], __fmul_rn(v0.w, v0.w));
        r[4] = __fadd_rn(r[4], __fmul_rn(v1.x, v1.x));
        r[5] = __fadd_rn(r[5], __fmul_rn(v1.y, v1.y));
        r[6] = __fadd_rn(r[6], __fmul_rn(v1.z, v1.z));
        r[7] = __fadd_rn(r[7], __fmul_rn(v1.w, v1.w));
        f16x8 h;
        h[0] = (_Float16)(v0.x * scale); h[1] = (_Float16)(v0.y * scale);
        h[2] = (_Float16)(v0.z * scale); h[3] = (_Float16)(v0.w * scale);
        h[4] = (_Float16)(v1.x * scale); h[5] = (_Float16)(v1.y * scale);
        h[6] = (_Float16)(v1.z * scale); h[7] = (_Float16)(v1.w * scale);
        *(f16x8*)(o + i * 8) = h;
    }
    return __fadd_rn(__fadd_rn(__fadd_rn(r[0], r[1]), __fadd_rn(r[2], r[3])),
                     __fadd_rn(__fadd_rn(r[4], r[5]), __fadd_rn(r[6], r[7])));
}

__global__ __launch_bounds__(256)
void prep2_kernel(const float* __restrict__ Z, const float* __restrict__ E,
                  _Float16* __restrict__ Zh, _Float16* __restrict__ Eh,
                  float* __restrict__ zz, float* __restrict__ ee,
                  unsigned int* __restrict__ cnt, unsigned int* __restrict__ rowmax,
                  double* __restrict__ lossAcc) {
    const int id = blockIdx.x * 256 + threadIdx.x;   // (NROWS+KCB)*4 total
    const int row = id >> 2, b = id & 3;
    if (id == 0) *lossAcc = 0.0;
    float blk;
    if (row < NROWS) {
        blk = blk128_sq_cvt(Z + (size_t)row * DIM + b * 128,
                            Zh + (size_t)row * DIM + b * 128, 1.0f);
    } else {
        const int k = row - NROWS;
        blk = blk128_sq_cvt(E + (size_t)k * DIM + b * 128,
                            Eh + (size_t)k * DIM + b * 128, 8192.0f);
    }
    float v1 = __fadd_rn(blk, __shfl_xor(blk, 1, 64));
    float v2 = __fadd_rn(v1, __shfl_xor(v1, 2, 64));
    if (b == 0) {
        if (row < NROWS) { zz[row] = v2; cnt[row] = 0; rowmax[row] = 0u; }
        else             ee[row - NROWS] = v2;
    }
}

// ---------------------------------------------------------------------------
// Screen v14 — r12 body VERBATIM (501 µs proven: 128x128 tile, BK=32,
// 4 waves, 16 KiB single-buffered LDS, plain __syncthreads, m97 K-loop,
// shared per-row atomicMax threshold, grid 16384 colTile-major).
// ONE change: __launch_bounds__(256,6) — r12's binding limit was the
// (256,4) cap itself (40.5% occupancy, VGPR 64 used vs 128 cap, LDS 16K
// allows 10 blocks). 6 waves/EU -> 6 blocks/CU target (96 KiB LDS), VGPR
// cap 85 with 64 used (margin; r13's cap-102 spill came from the two-half
// frag set, removed here). More resident blocks = more inter-block slip
// (r10->r12: 17%->24% MfmaUtil as blocks/CU rose).
// ---------------------------------------------------------------------------
__global__ __launch_bounds__(256, 6)
void screen_kernel(const _Float16* __restrict__ Zh, const _Float16* __restrict__ Eh,
                   unsigned int* __restrict__ cnt, unsigned int* __restrict__ cand,
                   unsigned int* __restrict__ rowmax, const int cap) {
    __shared__ __align__(16) char lds[16384];   // A 8 KiB + B 8 KiB

    const int tid = threadIdx.x;
    const int l = tid & 63;
    const int w = tid >> 6;           // wave 0..3
    const int wrow = w >> 1;          // 0..1
    const int wcol = w & 1;           // 0..1
    const int rowBase = (int)(blockIdx.x & 255) * 128;
    const int colBase = (int)(blockIdx.x >> 8) * 128;

    // per-thread staging constants: units u = tid + i*256, i in {0,1}
    // A: row = u>>2, pos = u&3, swizzled src slot = pos ^ ((row>>1)&3)
#define STAGE(ks) do {                                                         \
        _Pragma("unroll")                                                      \
        for (int _i = 0; _i < 2; ++_i) {                                       \
            const int _u = tid + _i * 256;                                     \
            const int _r = _u >> 2;                                            \
            const int _s = (_u & 3) ^ ((_r >> 1) & 3);                         \
            gl_lds16(Zh + (size_t)(rowBase + _r) * DIM + (ks) * 32 + _s * 8,   \
                     lds + (w * 64 + _i * 256) * 16 + l * 16);                 \
            gl_lds16(Eh + (size_t)(colBase + _r) * DIM + (ks) * 32 + _s * 8,   \
                     lds + 8192 + (w * 64 + _i * 256) * 16 + l * 16);          \
        }                                                                      \
    } while (0)

    // frag byte offsets (step-invariant; r6/r12 algebra, 0-conflict)
    int offA[4], offB[4];
#pragma unroll
    for (int m = 0; m < 4; ++m) {
        const int rr = wrow * 64 + m * 16 + (l & 15);
        offA[m] = (rr * 4 + ((l >> 4) ^ ((rr >> 1) & 3))) * 16;
    }
#pragma unroll
    for (int n = 0; n < 4; ++n) {
        const int c = wcol * 64 + n * 16 + (l & 15);
        offB[n] = 8192 + (c * 4 + ((l >> 4) ^ ((c >> 1) & 3))) * 16;
    }

    f32x4 acc[4][4];
#pragma unroll
    for (int m = 0; m < 4; ++m)
#pragma unroll
        for (int n = 0; n < 4; ++n) acc[m][n] = (f32x4){0.f, 0.f, 0.f, 0.f};

    // m97 K-loop: stage -> sync (vmcnt drain) -> read+MFMA -> sync
    for (int ks = 0; ks < 16; ++ks) {
        STAGE(ks);
        __syncthreads();
        f16x8 af[4], bf[4];
#pragma unroll
        for (int m = 0; m < 4; ++m) af[m] = *(const f16x8*)(lds + offA[m]);
#pragma unroll
        for (int n = 0; n < 4; ++n) bf[n] = *(const f16x8*)(lds + offB[n]);
#pragma unroll
        for (int m = 0; m < 4; ++m)
#pragma unroll
            for (int n = 0; n < 4; ++n)
                acc[m][n] = __builtin_amdgcn_mfma_f32_16x16x32_f16(af[m], bf[n], acc[m][n], 0, 0, 0);
        if (ks < 15) __syncthreads();
    }

    // epilogue: shared-rowmax screen + packed append (r12 verbatim)
#pragma unroll
    for (int m = 0; m < 4; ++m) {
#pragma unroll
        for (int r = 0; r < 4; ++r) {
            float mx = fmaxf(fmaxf(acc[m][0][r], acc[m][1][r]),
                             fmaxf(acc[m][2][r], acc[m][3][r]));
#pragma unroll
            for (int off = 1; off < 16; off <<= 1)
                mx = fmaxf(mx, __shfl_xor(mx, off, 64));
            const int rowg = rowBase + wrow * 64 + m * 16 + (l >> 4) * 4 + r;
            const float mxs = fmaxf(mx, -256.0f) + SCORE_OFS;   // positive
            unsigned old = 0;
            if ((l & 15) == 0)
                old = atomicMax(&rowmax[rowg], __float_as_uint(mxs));
            old = __shfl(old, l & 48, 64);   // broadcast group leader's old
            const float cur = fmaxf(__uint_as_float(old), mxs);
            const float thr = cur - SCORE_OFS - THR;
#pragma unroll
            for (int n = 0; n < 4; ++n) {
                if (acc[m][n][r] >= thr) {
                    unsigned pos = atomicAdd(&cnt[rowg], 1u);
                    if (pos < (unsigned)cap) {
                        unsigned kidx = (unsigned)(colBase + wcol * 64 + n * 16 + (l & 15));
                        float sc = fmaxf(acc[m][n][r] + SCORE_OFS, 1.0f);
                        cand[(size_t)rowg * cap + pos] =
                            (__float_as_uint(sc) & 0xFFFFE000u) | kidx;
                    }
                }
            }
        }
    }
#undef STAGE
}

// ---------------------------------------------------------------------------
// finish: prune via packed scores, exact rescore (bit-identical chain),
// gather + loss. c > cap or c == 0 -> exact full 8192-code scan.
// [r10/r11/r12-proven, verbatim]
// ---------------------------------------------------------------------------
__global__ __launch_bounds__(256)
void finish_kernel(const float* __restrict__ Z, const float* __restrict__ E,
                   const float* __restrict__ zz, const float* __restrict__ ee,
                   const unsigned int* __restrict__ cnt,
                   const unsigned int* __restrict__ cand,
                   float* __restrict__ outZ, float* __restrict__ outIdxF,
                   double* __restrict__ lossAcc, const int cap) {
    __shared__ double psum[4];
    const int tid = threadIdx.x;
    const int l = tid & 63;
    const int w = tid >> 6;
    double s = 0.0;

    for (int j = 0; j < 8; ++j) {
        const int row = blockIdx.x * 32 + w * 8 + j;
        const unsigned c = cnt[row];
        int kk;
        if (c == 1) {
            kk = (int)(cand[(size_t)row * cap] & 0x1FFFu);
        } else if (c >= 2 && c <= (unsigned)cap) {
            const unsigned key1 = (l < (int)c) ? cand[(size_t)row * cap + l] : 0u;
            const unsigned key2 = ((int)c > 64 && l + 64 < (int)c)
                                      ? cand[(size_t)row * cap + l + 64] : 0u;
            const float s1 = __uint_as_float(key1 & 0xFFFFE000u);
            const float s2 = __uint_as_float(key2 & 0xFFFFE000u);
            float smax = fmaxf(s1, s2);
#pragma unroll
            for (int off = 1; off < 64; off <<= 1)
                smax = fmaxf(smax, __shfl_xor(smax, off, 64));
            const float cut = smax - PRUNE_MARGIN;

            float d2 = __builtin_inff();
            int kl = 0x7FFFFFFF;
            const float4* zr4 = (const float4*)(Z + (size_t)row * DIM);
            if (l < (int)c && s1 >= cut) {
                int k = (int)(key1 & 0x1FFFu);
                const float4* er4 = (const float4*)(E + (size_t)k * DIM);
                float acc = 0.0f;
#pragma unroll 8
                for (int i = 0; i < DIM / 4; ++i) {
                    float4 z4 = zr4[i], e4 = er4[i];
                    acc = __builtin_fmaf(z4.x, e4.x, acc);
                    acc = __builtin_fmaf(z4.y, e4.y, acc);
                    acc = __builtin_fmaf(z4.z, e4.z, acc);
                    acc = __builtin_fmaf(z4.w, e4.w, acc);
                }
                float t = __builtin_fmaf(-2.0f, acc, zz[row]);
                d2 = __fadd_rn(t, ee[k]);
                kl = k;
            }
            if ((int)c > 64 && l + 64 < (int)c && s2 >= cut) {
                int k = (int)(key2 & 0x1FFFu);
                const float4* er4 = (const float4*)(E + (size_t)k * DIM);
                float acc = 0.0f;
#pragma unroll 8
                for (int i = 0; i < DIM / 4; ++i) {
                    float4 z4 = zr4[i], e4 = er4[i];
                    acc = __builtin_fmaf(z4.x, e4.x, acc);
                    acc = __builtin_fmaf(z4.y, e4.y, acc);
                    acc = __builtin_fmaf(z4.z, e4.z, acc);
                    acc = __builtin_fmaf(z4.w, e4.w, acc);
                }
                float t = __builtin_fmaf(-2.0f, acc, zz[row]);
                float d = __fadd_rn(t, ee[k]);
                if (d < d2 || (d == d2 && k < kl)) { d2 = d; kl = k; }
            }
#pragma unroll
            for (int off = 32; off > 0; off >>= 1) {
                float od = __shfl_down(d2, off, 64);
                int ok = __shfl_down(kl, off, 64);
                if (od < d2 || (od == d2 && ok < kl)) { d2 = od; kl = ok; }
            }
            kk = __shfl(kl, 0, 64);
        } else {
            // overflow (c > cap) or degenerate (c == 0): exact full scan
            float d2 = __builtin_inff();
            int kl = 0x7FFFFFFF;
            const float4* zr4 = (const float4*)(Z + (size_t)row * DIM);
            for (int k = l; k < KCB; k += 64) {
                const float4* er4 = (const float4*)(E + (size_t)k * DIM);
                float acc = 0.0f;
#pragma unroll 8
                for (int i = 0; i < DIM / 4; ++i) {
                    float4 z4 = zr4[i], e4 = er4[i];
                    acc = __builtin_fmaf(z4.x, e4.x, acc);
                    acc = __builtin_fmaf(z4.y, e4.y, acc);
                    acc = __builtin_fmaf(z4.z, e4.z, acc);
                    acc = __builtin_fmaf(z4.w, e4.w, acc);
                }
                float t = __builtin_fmaf(-2.0f, acc, zz[row]);
                float d = __fadd_rn(t, ee[k]);
                if (d < d2) { d2 = d; kl = k; }   // per-lane k ascending
            }
#pragma unroll
            for (int off = 32; off > 0; off >>= 1) {
                float od = __shfl_down(d2, off, 64);
                int ok = __shfl_down(kl, off, 64);
                if (od < d2 || (od == d2 && ok < kl)) { d2 = od; kl = ok; }
            }
            kk = __shfl(kl, 0, 64);
        }
        const float* zr = Z + (size_t)row * DIM;
        const float* er = E + (size_t)kk * DIM;
        float* orow = outZ + (size_t)row * DIM;
#pragma unroll
        for (int i = 0; i < 2; ++i) {
            int off = (l + i * 64) * 4;
            float4 z4 = *(const float4*)(zr + off);
            float4 e4 = *(const float4*)(er + off);
            float dx = __fsub_rn(e4.x, z4.x);
            float dy = __fsub_rn(e4.y, z4.y);
            float dz = __fsub_rn(e4.z, z4.z);
            float dw = __fsub_rn(e4.w, z4.w);
            float4 st;
            st.x = __fadd_rn(z4.x, dx);
            st.y = __fadd_rn(z4.y, dy);
            st.z = __fadd_rn(z4.z, dz);
            st.w = __fadd_rn(z4.w, dw);
            *(float4*)(orow + off) = st;
            s += (double)dx * dx + (double)dy * dy + (double)dz * dz + (double)dw * dw;
        }
        if (l == 0) outIdxF[row] = (float)kk;
    }
#pragma unroll
    for (int o = 32; o > 0; o >>= 1) s += __shfl_down(s, o, 64);
    if (l == 0) psum[w] = s;
    __syncthreads();
    if (tid == 0)
        atomicAdd(lossAcc, psum[0] + psum[1] + psum[2] + psum[3]);
}

__global__ void finalize_kernel(const double* __restrict__ lossAcc,
                                float* __restrict__ outLoss) {
    double m = *lossAcc / (double)((size_t)NROWS * DIM);
    float mf = (float)m;
    float c = __fmul_rn(0.25f, mf);
    *outLoss = __fadd_rn(c, mf);
}

// ---------------------------------------------------------------------------
// Fallback (ws too small): round-1 proven-correct VALU path, verbatim.
// ---------------------------------------------------------------------------
__device__ __forceinline__ float pairwise512_sq(const float* __restrict__ p) {
    float blk[4];
#pragma unroll
    for (int b = 0; b < 4; ++b) {
        const float* a = p + b * 128;
        float r[8];
#pragma unroll
        for (int j = 0; j < 8; ++j) r[j] = __fmul_rn(a[j], a[j]);
#pragma unroll
        for (int i = 8; i < 128; i += 8) {
#pragma unroll
            for (int j = 0; j < 8; ++j)
                r[j] = __fadd_rn(r[j], __fmul_rn(a[i + j], a[i + j]));
        }
        blk[b] = __fadd_rn(__fadd_rn(__fadd_rn(r[0], r[1]), __fadd_rn(r[2], r[3])),
                           __fadd_rn(__fadd_rn(r[4], r[5]), __fadd_rn(r[6], r[7])));
    }
    return __fadd_rn(__fadd_rn(blk[0], blk[1]), __fadd_rn(blk[2], blk[3]));
}

__global__ void ee_kernel(const float* __restrict__ E, float* __restrict__ ee) {
    int k = blockIdx.x * blockDim.x + threadIdx.x;
    if (k < KCB) ee[k] = pairwise512_sq(E + (size_t)k * DIM);
}

__global__ __launch_bounds__(512, 2)
void argmin_fallback(const float* __restrict__ Z, const float* __restrict__ E,
                     const float* __restrict__ ee, int* __restrict__ outIdx) {
    __shared__ __align__(16) char smem[(32 * 132 + 32 * 260) * 4];
    float (*As)[132] = (float (*)[132])smem;
    float (*Bs)[260] = (float (*)[260])(smem + 32 * 132 * 4);
    __shared__ float zzs[128];
    const int tid = threadIdx.x;
    const int tx = tid & 31;
    const int ty = tid >> 5;
    const int rowBase = blockIdx.x * 128;
    if (tid < 128) zzs[tid] = pairwise512_sq(Z + (size_t)(rowBase + tid) * DIM);
    __syncthreads();
    float zz[8];
#pragma unroll
    for (int m = 0; m < 8; ++m) zz[m] = zzs[ty * 8 + m];
    float bestV[8]; int bestI[8];
#pragma unroll
    for (int m = 0; m < 8; ++m) { bestV[m] = __builtin_inff(); bestI[m] = 0; }
    for (int tile = 0; tile < 32; ++tile) {
        float acc[8][8];
#pragma unroll
        for (int m = 0; m < 8; ++m)
#pragma unroll
            for (int n = 0; n < 8; ++n) acc[m][n] = 0.0f;
        for (int kc = 0; kc < DIM; kc += 32) {
            __syncthreads();
#pragma unroll
            for (int i = 0; i < 2; ++i) {
                int id4 = tid + i * 512;
                int r = id4 >> 3, c = id4 & 7;
                float4 v = *(const float4*)(Z + (size_t)(rowBase + r) * DIM + kc + c * 4);
                As[c * 4 + 0][r] = v.x; As[c * 4 + 1][r] = v.y;
                As[c * 4 + 2][r] = v.z; As[c * 4 + 3][r] = v.w;
            }
#pragma unroll
            for (int i = 0; i < 4; ++i) {
                int id4 = tid + i * 512;
                int r = id4 >> 3, c = id4 & 7;
                float4 v = *(const float4*)(E + (size_t)(tile * 256 + r) * DIM + kc + c * 4);
                Bs[c * 4 + 0][r] = v.x; Bs[c * 4 + 1][r] = v.y;
                Bs[c * 4 + 2][r] = v.z; Bs[c * 4 + 3][r] = v.w;
            }
            __syncthreads();
#pragma unroll
            for (int kk = 0; kk < 32; ++kk) {
                float a[8], b[8];
                *(float4*)&a[0] = *(const float4*)&As[kk][ty * 8];
                *(float4*)&a[4] = *(const float4*)&As[kk][ty * 8 + 4];
                *(float4*)&b[0] = *(const float4*)&Bs[kk][tx * 8];
                *(float4*)&b[4] = *(const float4*)&Bs[kk][tx * 8 + 4];
#pragma unroll
                for (int m = 0; m < 8; ++m)
#pragma unroll
                    for (int n = 0; n < 8; ++n)
                        acc[m][n] = __builtin_fmaf(a[m], b[n], acc[m][n]);
            }
        }
#pragma unroll
        for (int m = 0; m < 8; ++m) {
#pragma unroll
            for (int n = 0; n < 8; ++n) {
                float t = __builtin_fmaf(-2.0f, acc[m][n], zz[m]);
                float d2 = __fadd_rn(t, ee[tile * 256 + tx * 8 + n]);
                int kidx = tile * 256 + tx * 8 + n;
                if (d2 < bestV[m]) { bestV[m] = d2; bestI[m] = kidx; }
            }
        }
    }
    __syncthreads();
    float (*redV)[33] = (float (*)[33])smem;
    int   (*redI)[33] = (int (*)[33])(smem + 128 * 33 * 4);
#pragma unroll
    for (int m = 0; m < 8; ++m) {
        redV[ty * 8 + m][tx] = bestV[m];
        redI[ty * 8 + m][tx] = bestI[m];
    }
    __syncthreads();
    if (tid < 128) {
        float bv = redV[tid][0]; int bi = redI[tid][0];
        for (int j = 1; j < 32; ++j) {
            float v = redV[tid][j]; int ii = redI[tid][j];
            if (v < bv || (v == bv && ii < bi)) { bv = v; bi = ii; }
        }
        outIdx[rowBase + tid] = bi;
    }
}

__global__ void gather_kernel(const float* __restrict__ Z, const float* __restrict__ E,
                              const int* __restrict__ idx, float* __restrict__ outZ,
                              float* __restrict__ outIdxF, double* __restrict__ lossAcc) {
    int row = blockIdx.x;
    int t = threadIdx.x;  // 64
    int k = idx[row];
    const float* zr = Z + (size_t)row * DIM;
    const float* er = E + (size_t)k * DIM;
    float* orow = outZ + (size_t)row * DIM;
    double s = 0.0;
#pragma unroll
    for (int i = 0; i < 2; ++i) {
        int off = (t + i * 64) * 4;
        float4 z4 = *(const float4*)(zr + off);
        float4 e4 = *(const float4*)(er + off);
        float dx = __fsub_rn(e4.x, z4.x);
        float dy = __fsub_rn(e4.y, z4.y);
        float dz = __fsub_rn(e4.z, z4.z);
        float dw = __fsub_rn(e4.w, z4.w);
        float4 st;
        st.x = __fadd_rn(z4.x, dx);
        st.y = __fadd_rn(z4.y, dy);
        st.z = __fadd_rn(z4.z, dz);
        st.w = __fadd_rn(z4.w, dw);
        *(float4*)(orow + off) = st;
        s += (double)dx * dx + (double)dy * dy + (double)dz * dz + (double)dw * dw;
    }
#pragma unroll
    for (int o = 32; o > 0; o >>= 1) s += __shfl_down(s, o, 64);
    if (t == 0) {
        atomicAdd(lossAcc, s);
        outIdxF[row] = (float)k;
    }
}

// ---------------------------------------------------------------------------
extern "C" void kernel_launch(void* const* d_in, const int* in_sizes, int n_in,
                              void* d_out, int out_size, void* d_ws, size_t ws_size,
                              hipStream_t stream) {
    const float* Z = (const float*)d_in[0];
    const float* E = (const float*)d_in[1];
    float* out = (float*)d_out;
    float* zq_out = out;
    float* loss_out = out + (size_t)NROWS * DIM;
    float* idxf_out = loss_out + 1;

    if (ws_size >= WS_NEEDED_64) {
        const int cap = (ws_size >= WS_NEEDED_128) ? 128 : 64;
        _Float16* Zh = (_Float16*)((char*)d_ws + OFF_ZH);
        _Float16* Eh = (_Float16*)((char*)d_ws + OFF_EH);
        float* ee = (float*)((char*)d_ws + OFF_EE);
        float* zz = (float*)((char*)d_ws + OFF_ZZ);
        unsigned int* cnt = (unsigned int*)((char*)d_ws + OFF_CNT);
        unsigned int* cand = (unsigned int*)((char*)d_ws + OFF_CAND);
        unsigned int* rowmax = (unsigned int*)((char*)d_ws + OFF_CAND
                                               + (size_t)NROWS * cap * 4);
        double* lossAcc = (double*)((char*)d_ws + OFF_LOSS);

        prep2_kernel<<<(NROWS + KCB) * 4 / 256, 256, 0, stream>>>(Z, E, Zh, Eh, zz, ee,
                                                                  cnt, rowmax, lossAcc);
        screen_kernel<<<256 * 64, 256, 0, stream>>>(Zh, Eh, cnt, cand, rowmax, cap);
        finish_kernel<<<NROWS / 32, 256, 0, stream>>>(Z, E, zz, ee, cnt, cand,
                                                      zq_out, idxf_out, lossAcc, cap);
        finalize_kernel<<<1, 1, 0, stream>>>(lossAcc, loss_out);
    } else {
        float* ee = (float*)d_ws;
        int* idx = (int*)((char*)d_ws + 32768);
        double* lossAcc = (double*)((char*)d_ws + 163840);
        hipMemsetAsync(lossAcc, 0, sizeof(double), stream);
        ee_kernel<<<KCB / 256, 256, 0, stream>>>(E, ee);
        argmin_fallback<<<NROWS / 128, 512, 0, stream>>>(Z, E, ee, idx);
        gather_kernel<<<NROWS, 64, 0, stream>>>(Z, E, idx, zq_out, idxf_out, lossAcc);
        finalize_kernel<<<1, 1, 0, stream>>>(lossAcc, loss_out);
    }
}

// Round 16
// 736.172 us; speedup vs baseline: 3.3638x; 3.3524x over previous
//
#include <hip/hip_runtime.h>
#include <math.h>

#define DIM    512
#define KCB    8192
#define NROWS  32768

typedef _Float16 f16x8 __attribute__((ext_vector_type(8)));
typedef float    f32x4 __attribute__((ext_vector_type(4)));

// ---- workspace layout (main path) ----
#define OFF_ZH    0ull                    // f16 Z  [32768][512] = 33554432 B
#define OFF_EH    33554432ull             // f16 E*8192 [8192][512] = 8388608 B
#define OFF_EE    41943040ull             // f32 ee [8192]
#define OFF_ZZ    41975808ull             // f32 zz [32768]
#define OFF_CNT   42106880ull             // u32 cnt[32768]
#define OFF_LOSS  42237952ull             // f64 loss accumulator
#define OFF_CAND  42237960ull             // u32 cand[32768][cap] (packed score|idx)
// rowmax u32[32768] follows cand; sizes:
#define WS_NEEDED_64  50757640ull         // cap = 64  (cand 8 MB + rowmax 128 KB)
#define WS_NEEDED_128 59146248ull         // cap = 128 (cand 16 MB + rowmax 128 KB)
// screen keeps k if dot16_scaled >= curmax - THR (E scaled by 2^13; folds ee
// and all f16 error into the margin; r3..r13-proven). curmax = max(shared
// per-row atomicMax value, local wave max) — any value <= true global max16
// only loosens the threshold, correctness unchanged.
#define THR 2.048f
// candidate entry: high 19 bits = float bits of (score+512) with low 13
// mantissa bits zeroed (quant err <= 0.5; clamped positive -> bit-monotone);
// low 13 bits = k. finish prunes at (global best - 2.6): winner needs
// 0.98 (proven slack) + 0.5 (quant) = 1.48 -> 2.6 safe. [r11/r12/r13-proven]
#define SCORE_OFS 512.0f
#define PRUNE_MARGIN 2.6f

__device__ __forceinline__ void gl_lds16(const void* g, void* l) {
    __builtin_amdgcn_global_load_lds(
        (const __attribute__((address_space(1))) unsigned int*)g,
        (__attribute__((address_space(3))) unsigned int*)l, 16, 0, 0);
}

// ---------------------------------------------------------------------------
// prep2: fused norms + f16 conversion, one pass over Z and E (r13-proven).
// ---------------------------------------------------------------------------
__device__ __forceinline__ float blk128_sq_cvt(const float* __restrict__ p,
                                               _Float16* __restrict__ o, float scale) {
    const float4* a4 = (const float4*)p;
    float4 v0 = a4[0], v1 = a4[1];
    float r[8];
    r[0] = __fmul_rn(v0.x, v0.x); r[1] = __fmul_rn(v0.y, v0.y);
    r[2] = __fmul_rn(v0.z, v0.z); r[3] = __fmul_rn(v0.w, v0.w);
    r[4] = __fmul_rn(v1.x, v1.x); r[5] = __fmul_rn(v1.y, v1.y);
    r[6] = __fmul_rn(v1.z, v1.z); r[7] = __fmul_rn(v1.w, v1.w);
    {
        f16x8 h;
        h[0] = (_Float16)(v0.x * scale); h[1] = (_Float16)(v0.y * scale);
        h[2] = (_Float16)(v0.z * scale); h[3] = (_Float16)(v0.w * scale);
        h[4] = (_Float16)(v1.x * scale); h[5] = (_Float16)(v1.y * scale);
        h[6] = (_Float16)(v1.z * scale); h[7] = (_Float16)(v1.w * scale);
        *(f16x8*)o = h;
    }
#pragma unroll
    for (int i = 1; i < 16; ++i) {
        v0 = a4[i * 2]; v1 = a4[i * 2 + 1];
        r[0] = __fadd_rn(r[0], __fmul_rn(v0.x, v0.x));
        r[1] = __fadd_rn(r[1], __fmul_rn(v0.y, v0.y));
        r[2] = __fadd_rn(r[2], __fmul_rn(v0.z, v0.z));
        r[3] = __fadd_rn(r[3], __fmul_rn(v0.w, v0.w));
        r[4] = __fadd_rn(r[4], __fmul_rn(v1.x, v1.x));
        r[5] = __fadd_rn(r[5], __fmul_rn(v1.y, v1.y));
        r[6] = __fadd_rn(r[6], __fmul_rn(v1.z, v1.z));
        r[7] = __fadd_rn(r[7], __fmul_rn(v1.w, v1.w));
        f16x8 h;
        h[0] = (_Float16)(v0.x * scale); h[1] = (_Float16)(v0.y * scale);
        h[2] = (_Float16)(v0.z * scale); h[3] = (_Float16)(v0.w * scale);
        h[4] = (_Float16)(v1.x * scale); h[5] = (_Float16)(v1.y * scale);
        h[6] = (_Float16)(v1.z * scale); h[7] = (_Float16)(v1.w * scale);
        *(f16x8*)(o + i * 8) = h;
    }
    return __fadd_rn(__fadd_rn(__fadd_rn(r[0], r[1]), __fadd_rn(r[2], r[3])),
                     __fadd_rn(__fadd_rn(r[4], r[5]), __fadd_rn(r[6], r[7])));
}

__global__ __launch_bounds__(256)
void prep2_kernel(const float* __restrict__ Z, const float* __restrict__ E,
                  _Float16* __restrict__ Zh, _Float16* __restrict__ Eh,
                  float* __restrict__ zz, float* __restrict__ ee,
                  unsigned int* __restrict__ cnt, unsigned int* __restrict__ rowmax,
                  double* __restrict__ lossAcc) {
    const int id = blockIdx.x * 256 + threadIdx.x;   // (NROWS+KCB)*4 total
    const int row = id >> 2, b = id & 3;
    if (id == 0) *lossAcc = 0.0;
    float blk;
    if (row < NROWS) {
        blk = blk128_sq_cvt(Z + (size_t)row * DIM + b * 128,
                            Zh + (size_t)row * DIM + b * 128, 1.0f);
    } else {
        const int k = row - NROWS;
        blk = blk128_sq_cvt(E + (size_t)k * DIM + b * 128,
                            Eh + (size_t)k * DIM + b * 128, 8192.0f);
    }
    float v1 = __fadd_rn(blk, __shfl_xor(blk, 1, 64));
    float v2 = __fadd_rn(v1, __shfl_xor(v1, 2, 64));
    if (b == 0) {
        if (row < NROWS) { zz[row] = v2; cnt[row] = 0; rowmax[row] = 0u; }
        else             ee[row - NROWS] = v2;
    }
}

// ---------------------------------------------------------------------------
// Screen v16 — r12 body + 2-phase LDS double-buffer (catalog T3-minimum),
// launch_bounds RESTORED to (256,4) (the unified VGPR+AGPR footprint is
// exactly 128 regs/thread: 64-f32 acc in AGPR + ~64 VGPR; caps 102/85
// spilled in r13/r15 with 5-50x scratch traffic). LDS 2 x 16 KiB; per kstep:
// STAGE(ks+1 -> other buf) [no wait] -> read frags cur -> 16 MFMA ->
// __syncthreads (implicit vmcnt(0) completes next buffer AND proves current
// reads retired before its later overwrite). Barriers 31 -> 17 per block;
// the DMA hides under the compute phase instead of being serially exposed.
// Grid 16384 colTile-major + shared per-row atomicMax threshold (r12-proven).
// ---------------------------------------------------------------------------
__global__ __launch_bounds__(256, 4)
void screen_kernel(const _Float16* __restrict__ Zh, const _Float16* __restrict__ Eh,
                   unsigned int* __restrict__ cnt, unsigned int* __restrict__ cand,
                   unsigned int* __restrict__ rowmax, const int cap) {
    __shared__ __align__(16) char lds[2 * 16384];   // 2 x (A 8 KiB + B 8 KiB)

    const int tid = threadIdx.x;
    const int l = tid & 63;
    const int w = tid >> 6;           // wave 0..3
    const int wrow = w >> 1;          // 0..1
    const int wcol = w & 1;           // 0..1
    const int rowBase = (int)(blockIdx.x & 255) * 128;
    const int colBase = (int)(blockIdx.x >> 8) * 128;

    // per-thread staging constants (r12 verbatim + buffer base)
#define STAGE(ks, base) do {                                                   \
        _Pragma("unroll")                                                      \
        for (int _i = 0; _i < 2; ++_i) {                                       \
            const int _u = tid + _i * 256;                                     \
            const int _r = _u >> 2;                                            \
            const int _s = (_u & 3) ^ ((_r >> 1) & 3);                         \
            gl_lds16(Zh + (size_t)(rowBase + _r) * DIM + (ks) * 32 + _s * 8,   \
                     lds + (base) + (w * 64 + _i * 256) * 16 + l * 16);        \
            gl_lds16(Eh + (size_t)(colBase + _r) * DIM + (ks) * 32 + _s * 8,   \
                     lds + (base) + 8192 + (w * 64 + _i * 256) * 16 + l * 16); \
        }                                                                      \
    } while (0)

    // frag byte offsets (step-invariant; r6/r12 algebra, 0-conflict)
    int offA[4], offB[4];
#pragma unroll
    for (int m = 0; m < 4; ++m) {
        const int rr = wrow * 64 + m * 16 + (l & 15);
        offA[m] = (rr * 4 + ((l >> 4) ^ ((rr >> 1) & 3))) * 16;
    }
#pragma unroll
    for (int n = 0; n < 4; ++n) {
        const int c = wcol * 64 + n * 16 + (l & 15);
        offB[n] = 8192 + (c * 4 + ((l >> 4) ^ ((c >> 1) & 3))) * 16;
    }

    f32x4 acc[4][4];
#pragma unroll
    for (int m = 0; m < 4; ++m)
#pragma unroll
        for (int n = 0; n < 4; ++n) acc[m][n] = (f32x4){0.f, 0.f, 0.f, 0.f};

    // 2-phase K-loop: prologue fill buf0, then {stage-next | compute-cur}
    STAGE(0, 0);
    __syncthreads();                       // buf0 complete
    for (int ks = 0; ks < 16; ++ks) {
        const int cur = (ks & 1) * 16384;
        if (ks < 15) STAGE(ks + 1, 16384 - cur);   // fill other buffer, no wait
        const char* B = lds + cur;
        f16x8 af[4], bf[4];
#pragma unroll
        for (int m = 0; m < 4; ++m) af[m] = *(const f16x8*)(B + offA[m]);
#pragma unroll
        for (int n = 0; n < 4; ++n) bf[n] = *(const f16x8*)(B + offB[n]);
#pragma unroll
        for (int m = 0; m < 4; ++m)
#pragma unroll
            for (int n = 0; n < 4; ++n)
                acc[m][n] = __builtin_amdgcn_mfma_f32_16x16x32_f16(af[m], bf[n], acc[m][n], 0, 0, 0);
        if (ks < 15) __syncthreads();      // next buffer ready; my reads retired
    }

    // epilogue: shared-rowmax screen + packed append (r12 verbatim)
#pragma unroll
    for (int m = 0; m < 4; ++m) {
#pragma unroll
        for (int r = 0; r < 4; ++r) {
            float mx = fmaxf(fmaxf(acc[m][0][r], acc[m][1][r]),
                             fmaxf(acc[m][2][r], acc[m][3][r]));
#pragma unroll
            for (int off = 1; off < 16; off <<= 1)
                mx = fmaxf(mx, __shfl_xor(mx, off, 64));
            const int rowg = rowBase + wrow * 64 + m * 16 + (l >> 4) * 4 + r;
            const float mxs = fmaxf(mx, -256.0f) + SCORE_OFS;   // positive
            unsigned old = 0;
            if ((l & 15) == 0)
                old = atomicMax(&rowmax[rowg], __float_as_uint(mxs));
            old = __shfl(old, l & 48, 64);   // broadcast group leader's old
            const float cur = fmaxf(__uint_as_float(old), mxs);
            const float thr = cur - SCORE_OFS - THR;
#pragma unroll
            for (int n = 0; n < 4; ++n) {
                if (acc[m][n][r] >= thr) {
                    unsigned pos = atomicAdd(&cnt[rowg], 1u);
                    if (pos < (unsigned)cap) {
                        unsigned kidx = (unsigned)(colBase + wcol * 64 + n * 16 + (l & 15));
                        float sc = fmaxf(acc[m][n][r] + SCORE_OFS, 1.0f);
                        cand[(size_t)rowg * cap + pos] =
                            (__float_as_uint(sc) & 0xFFFFE000u) | kidx;
                    }
                }
            }
        }
    }
#undef STAGE
}

// ---------------------------------------------------------------------------
// finish: prune via packed scores, exact rescore (bit-identical chain),
// gather + loss. c > cap or c == 0 -> exact full 8192-code scan.
// [r10/r11/r12/r13-proven, verbatim]
// ---------------------------------------------------------------------------
__global__ __launch_bounds__(256)
void finish_kernel(const float* __restrict__ Z, const float* __restrict__ E,
                   const float* __restrict__ zz, const float* __restrict__ ee,
                   const unsigned int* __restrict__ cnt,
                   const unsigned int* __restrict__ cand,
                   float* __restrict__ outZ, float* __restrict__ outIdxF,
                   double* __restrict__ lossAcc, const int cap) {
    __shared__ double psum[4];
    const int tid = threadIdx.x;
    const int l = tid & 63;
    const int w = tid >> 6;
    double s = 0.0;

    for (int j = 0; j < 8; ++j) {
        const int row = blockIdx.x * 32 + w * 8 + j;
        const unsigned c = cnt[row];
        int kk;
        if (c == 1) {
            kk = (int)(cand[(size_t)row * cap] & 0x1FFFu);
        } else if (c >= 2 && c <= (unsigned)cap) {
            const unsigned key1 = (l < (int)c) ? cand[(size_t)row * cap + l] : 0u;
            const unsigned key2 = ((int)c > 64 && l + 64 < (int)c)
                                      ? cand[(size_t)row * cap + l + 64] : 0u;
            const float s1 = __uint_as_float(key1 & 0xFFFFE000u);
            const float s2 = __uint_as_float(key2 & 0xFFFFE000u);
            float smax = fmaxf(s1, s2);
#pragma unroll
            for (int off = 1; off < 64; off <<= 1)
                smax = fmaxf(smax, __shfl_xor(smax, off, 64));
            const float cut = smax - PRUNE_MARGIN;

            float d2 = __builtin_inff();
            int kl = 0x7FFFFFFF;
            const float4* zr4 = (const float4*)(Z + (size_t)row * DIM);
            if (l < (int)c && s1 >= cut) {
                int k = (int)(key1 & 0x1FFFu);
                const float4* er4 = (const float4*)(E + (size_t)k * DIM);
                float acc = 0.0f;
#pragma unroll 8
                for (int i = 0; i < DIM / 4; ++i) {
                    float4 z4 = zr4[i], e4 = er4[i];
                    acc = __builtin_fmaf(z4.x, e4.x, acc);
                    acc = __builtin_fmaf(z4.y, e4.y, acc);
                    acc = __builtin_fmaf(z4.z, e4.z, acc);
                    acc = __builtin_fmaf(z4.w, e4.w, acc);
                }
                float t = __builtin_fmaf(-2.0f, acc, zz[row]);
                d2 = __fadd_rn(t, ee[k]);
                kl = k;
            }
            if ((int)c > 64 && l + 64 < (int)c && s2 >= cut) {
                int k = (int)(key2 & 0x1FFFu);
                const float4* er4 = (const float4*)(E + (size_t)k * DIM);
                float acc = 0.0f;
#pragma unroll 8
                for (int i = 0; i < DIM / 4; ++i) {
                    float4 z4 = zr4[i], e4 = er4[i];
                    acc = __builtin_fmaf(z4.x, e4.x, acc);
                    acc = __builtin_fmaf(z4.y, e4.y, acc);
                    acc = __builtin_fmaf(z4.z, e4.z, acc);
                    acc = __builtin_fmaf(z4.w, e4.w, acc);
                }
                float t = __builtin_fmaf(-2.0f, acc, zz[row]);
                float d = __fadd_rn(t, ee[k]);
                if (d < d2 || (d == d2 && k < kl)) { d2 = d; kl = k; }
            }
#pragma unroll
            for (int off = 32; off > 0; off >>= 1) {
                float od = __shfl_down(d2, off, 64);
                int ok = __shfl_down(kl, off, 64);
                if (od < d2 || (od == d2 && ok < kl)) { d2 = od; kl = ok; }
            }
            kk = __shfl(kl, 0, 64);
        } else {
            // overflow (c > cap) or degenerate (c == 0): exact full scan
            float d2 = __builtin_inff();
            int kl = 0x7FFFFFFF;
            const float4* zr4 = (const float4*)(Z + (size_t)row * DIM);
            for (int k = l; k < KCB; k += 64) {
                const float4* er4 = (const float4*)(E + (size_t)k * DIM);
                float acc = 0.0f;
#pragma unroll 8
                for (int i = 0; i < DIM / 4; ++i) {
                    float4 z4 = zr4[i], e4 = er4[i];
                    acc = __builtin_fmaf(z4.x, e4.x, acc);
                    acc = __builtin_fmaf(z4.y, e4.y, acc);
                    acc = __builtin_fmaf(z4.z, e4.z, acc);
                    acc = __builtin_fmaf(z4.w, e4.w, acc);
                }
                float t = __builtin_fmaf(-2.0f, acc, zz[row]);
                float d = __fadd_rn(t, ee[k]);
                if (d < d2) { d2 = d; kl = k; }   // per-lane k ascending
            }
#pragma unroll
            for (int off = 32; off > 0; off >>= 1) {
                float od = __shfl_down(d2, off, 64);
                int ok = __shfl_down(kl, off, 64);
                if (od < d2 || (od == d2 && ok < kl)) { d2 = od; kl = ok; }
            }
            kk = __shfl(kl, 0, 64);
        }
        const float* zr = Z + (size_t)row * DIM;
        const float* er = E + (size_t)kk * DIM;
        float* orow = outZ + (size_t)row * DIM;
#pragma unroll
        for (int i = 0; i < 2; ++i) {
            int off = (l + i * 64) * 4;
            float4 z4 = *(const float4*)(zr + off);
            float4 e4 = *(const float4*)(er + off);
            float dx = __fsub_rn(e4.x, z4.x);
            float dy = __fsub_rn(e4.y, z4.y);
            float dz = __fsub_rn(e4.z, z4.z);
            float dw = __fsub_rn(e4.w, z4.w);
            float4 st;
            st.x = __fadd_rn(z4.x, dx);
            st.y = __fadd_rn(z4.y, dy);
            st.z = __fadd_rn(z4.z, dz);
            st.w = __fadd_rn(z4.w, dw);
            *(float4*)(orow + off) = st;
            s += (double)dx * dx + (double)dy * dy + (double)dz * dz + (double)dw * dw;
        }
        if (l == 0) outIdxF[row] = (float)kk;
    }
#pragma unroll
    for (int o = 32; o > 0; o >>= 1) s += __shfl_down(s, o, 64);
    if (l == 0) psum[w] = s;
    __syncthreads();
    if (tid == 0)
        atomicAdd(lossAcc, psum[0] + psum[1] + psum[2] + psum[3]);
}

__global__ void finalize_kernel(const double* __restrict__ lossAcc,
                                float* __restrict__ outLoss) {
    double m = *lossAcc / (double)((size_t)NROWS * DIM);
    float mf = (float)m;
    float c = __fmul_rn(0.25f, mf);
    *outLoss = __fadd_rn(c, mf);
}

// ---------------------------------------------------------------------------
// Fallback (ws too small): round-1 proven-correct VALU path, verbatim.
// ---------------------------------------------------------------------------
__device__ __forceinline__ float pairwise512_sq(const float* __restrict__ p) {
    float blk[4];
#pragma unroll
    for (int b = 0; b < 4; ++b) {
        const float* a = p + b * 128;
        float r[8];
#pragma unroll
        for (int j = 0; j < 8; ++j) r[j] = __fmul_rn(a[j], a[j]);
#pragma unroll
        for (int i = 8; i < 128; i += 8) {
#pragma unroll
            for (int j = 0; j < 8; ++j)
                r[j] = __fadd_rn(r[j], __fmul_rn(a[i + j], a[i + j]));
        }
        blk[b] = __fadd_rn(__fadd_rn(__fadd_rn(r[0], r[1]), __fadd_rn(r[2], r[3])),
                           __fadd_rn(__fadd_rn(r[4], r[5]), __fadd_rn(r[6], r[7])));
    }
    return __fadd_rn(__fadd_rn(blk[0], blk[1]), __fadd_rn(blk[2], blk[3]));
}

__global__ void ee_kernel(const float* __restrict__ E, float* __restrict__ ee) {
    int k = blockIdx.x * blockDim.x + threadIdx.x;
    if (k < KCB) ee[k] = pairwise512_sq(E + (size_t)k * DIM);
}

__global__ __launch_bounds__(512, 2)
void argmin_fallback(const float* __restrict__ Z, const float* __restrict__ E,
                     const float* __restrict__ ee, int* __restrict__ outIdx) {
    __shared__ __align__(16) char smem[(32 * 132 + 32 * 260) * 4];
    float (*As)[132] = (float (*)[132])smem;
    float (*Bs)[260] = (float (*)[260])(smem + 32 * 132 * 4);
    __shared__ float zzs[128];
    const int tid = threadIdx.x;
    const int tx = tid & 31;
    const int ty = tid >> 5;
    const int rowBase = blockIdx.x * 128;
    if (tid < 128) zzs[tid] = pairwise512_sq(Z + (size_t)(rowBase + tid) * DIM);
    __syncthreads();
    float zz[8];
#pragma unroll
    for (int m = 0; m < 8; ++m) zz[m] = zzs[ty * 8 + m];
    float bestV[8]; int bestI[8];
#pragma unroll
    for (int m = 0; m < 8; ++m) { bestV[m] = __builtin_inff(); bestI[m] = 0; }
    for (int tile = 0; tile < 32; ++tile) {
        float acc[8][8];
#pragma unroll
        for (int m = 0; m < 8; ++m)
#pragma unroll
            for (int n = 0; n < 8; ++n) acc[m][n] = 0.0f;
        for (int kc = 0; kc < DIM; kc += 32) {
            __syncthreads();
#pragma unroll
            for (int i = 0; i < 2; ++i) {
                int id4 = tid + i * 512;
                int r = id4 >> 3, c = id4 & 7;
                float4 v = *(const float4*)(Z + (size_t)(rowBase + r) * DIM + kc + c * 4);
                As[c * 4 + 0][r] = v.x; As[c * 4 + 1][r] = v.y;
                As[c * 4 + 2][r] = v.z; As[c * 4 + 3][r] = v.w;
            }
#pragma unroll
            for (int i = 0; i < 4; ++i) {
                int id4 = tid + i * 512;
                int r = id4 >> 3, c = id4 & 7;
                float4 v = *(const float4*)(E + (size_t)(tile * 256 + r) * DIM + kc + c * 4);
                Bs[c * 4 + 0][r] = v.x; Bs[c * 4 + 1][r] = v.y;
                Bs[c * 4 + 2][r] = v.z; Bs[c * 4 + 3][r] = v.w;
            }
            __syncthreads();
#pragma unroll
            for (int kk = 0; kk < 32; ++kk) {
                float a[8], b[8];
                *(float4*)&a[0] = *(const float4*)&As[kk][ty * 8];
                *(float4*)&a[4] = *(const float4*)&As[kk][ty * 8 + 4];
                *(float4*)&b[0] = *(const float4*)&Bs[kk][tx * 8];
                *(float4*)&b[4] = *(const float4*)&Bs[kk][tx * 8 + 4];
#pragma unroll
                for (int m = 0; m < 8; ++m)
#pragma unroll
                    for (int n = 0; n < 8; ++n)
                        acc[m][n] = __builtin_fmaf(a[m], b[n], acc[m][n]);
            }
        }
#pragma unroll
        for (int m = 0; m < 8; ++m) {
#pragma unroll
            for (int n = 0; n < 8; ++n) {
                float t = __builtin_fmaf(-2.0f, acc[m][n], zz[m]);
                float d2 = __fadd_rn(t, ee[tile * 256 + tx * 8 + n]);
                int kidx = tile * 256 + tx * 8 + n;
                if (d2 < bestV[m]) { bestV[m] = d2; bestI[m] = kidx; }
            }
        }
    }
    __syncthreads();
    float (*redV)[33] = (float (*)[33])smem;
    int   (*redI)[33] = (int (*)[33])(smem + 128 * 33 * 4);
#pragma unroll
    for (int m = 0; m < 8; ++m) {
        redV[ty * 8 + m][tx] = bestV[m];
        redI[ty * 8 + m][tx] = bestI[m];
    }
    __syncthreads();
    if (tid < 128) {
        float bv = redV[tid][0]; int bi = redI[tid][0];
        for (int j = 1; j < 32; ++j) {
            float v = redV[tid][j]; int ii = redI[tid][j];
            if (v < bv || (v == bv && ii < bi)) { bv = v; bi = ii; }
        }
        outIdx[rowBase + tid] = bi;
    }
}

__global__ void gather_kernel(const float* __restrict__ Z, const float* __restrict__ E,
                              const int* __restrict__ idx, float* __restrict__ outZ,
                              float* __restrict__ outIdxF, double* __restrict__ lossAcc) {
    int row = blockIdx.x;
    int t = threadIdx.x;  // 64
    int k = idx[row];
    const float* zr = Z + (size_t)row * DIM;
    const float* er = E + (size_t)k * DIM;
    float* orow = outZ + (size_t)row * DIM;
    double s = 0.0;
#pragma unroll
    for (int i = 0; i < 2; ++i) {
        int off = (t + i * 64) * 4;
        float4 z4 = *(const float4*)(zr + off);
        float4 e4 = *(const float4*)(er + off);
        float dx = __fsub_rn(e4.x, z4.x);
        float dy = __fsub_rn(e4.y, z4.y);
        float dz = __fsub_rn(e4.z, z4.z);
        float dw = __fsub_rn(e4.w, z4.w);
        float4 st;
        st.x = __fadd_rn(z4.x, dx);
        st.y = __fadd_rn(z4.y, dy);
        st.z = __fadd_rn(z4.z, dz);
        st.w = __fadd_rn(z4.w, dw);
        *(float4*)(orow + off) = st;
        s += (double)dx * dx + (double)dy * dy + (double)dz * dz + (double)dw * dw;
    }
#pragma unroll
    for (int o = 32; o > 0; o >>= 1) s += __shfl_down(s, o, 64);
    if (t == 0) {
        atomicAdd(lossAcc, s);
        outIdxF[row] = (float)k;
    }
}

// ---------------------------------------------------------------------------
extern "C" void kernel_launch(void* const* d_in, const int* in_sizes, int n_in,
                              void* d_out, int out_size, void* d_ws, size_t ws_size,
                              hipStream_t stream) {
    const float* Z = (const float*)d_in[0];
    const float* E = (const float*)d_in[1];
    float* out = (float*)d_out;
    float* zq_out = out;
    float* loss_out = out + (size_t)NROWS * DIM;
    float* idxf_out = loss_out + 1;

    if (ws_size >= WS_NEEDED_64) {
        const int cap = (ws_size >= WS_NEEDED_128) ? 128 : 64;
        _Float16* Zh = (_Float16*)((char*)d_ws + OFF_ZH);
        _Float16* Eh = (_Float16*)((char*)d_ws + OFF_EH);
        float* ee = (float*)((char*)d_ws + OFF_EE);
        float* zz = (float*)((char*)d_ws + OFF_ZZ);
        unsigned int* cnt = (unsigned int*)((char*)d_ws + OFF_CNT);
        unsigned int* cand = (unsigned int*)((char*)d_ws + OFF_CAND);
        unsigned int* rowmax = (unsigned int*)((char*)d_ws + OFF_CAND
                                               + (size_t)NROWS * cap * 4);
        double* lossAcc = (double*)((char*)d_ws + OFF_LOSS);

        prep2_kernel<<<(NROWS + KCB) * 4 / 256, 256, 0, stream>>>(Z, E, Zh, Eh, zz, ee,
                                                                  cnt, rowmax, lossAcc);
        screen_kernel<<<256 * 64, 256, 0, stream>>>(Zh, Eh, cnt, cand, rowmax, cap);
        finish_kernel<<<NROWS / 32, 256, 0, stream>>>(Z, E, zz, ee, cnt, cand,
                                                      zq_out, idxf_out, lossAcc, cap);
        finalize_kernel<<<1, 1, 0, stream>>>(lossAcc, loss_out);
    } else {
        float* ee = (float*)d_ws;
        int* idx = (int*)((char*)d_ws + 32768);
        double* lossAcc = (double*)((char*)d_ws + 163840);
        hipMemsetAsync(lossAcc, 0, sizeof(double), stream);
        ee_kernel<<<KCB / 256, 256, 0, stream>>>(E, ee);
        argmin_fallback<<<NROWS / 128, 512, 0, stream>>>(Z, E, ee, idx);
        gather_kernel<<<NROWS, 64, 0, stream>>>(Z, E, idx, zq_out, idxf_out, lossAcc);
        finalize_kernel<<<1, 1, 0, stream>>>(lossAcc, loss_out);
    }
}

// Round 17
// 717.903 us; speedup vs baseline: 3.4494x; 1.0254x over previous
//
#include <hip/hip_runtime.h>
#include <math.h>

#define DIM    512
#define KCB    8192
#define NROWS  32768

typedef _Float16 f16x8 __attribute__((ext_vector_type(8)));
typedef float    f32x4 __attribute__((ext_vector_type(4)));

// ---- workspace layout (main path) ----
#define OFF_ZH    0ull                    // f16 Z  [32768][512] = 33554432 B
#define OFF_EH    33554432ull             // f16 E*8192 [8192][512] = 8388608 B
#define OFF_EE    41943040ull             // f32 ee [8192]
#define OFF_ZZ    41975808ull             // f32 zz [32768]
#define OFF_CNT   42106880ull             // u32 cnt[32768]
#define OFF_LOSS  42237952ull             // f64 loss accumulator
#define OFF_CAND  42237960ull             // u32 cand[32768][cap] (packed score|idx)
// rowmax u32[32768] follows cand; sizes:
#define WS_NEEDED_64  50757640ull         // cap = 64  (cand 8 MB + rowmax 128 KB)
#define WS_NEEDED_128 59146248ull         // cap = 128 (cand 16 MB + rowmax 128 KB)
// screen keeps k if dot16_scaled >= curmax - THR (E scaled by 2^13; folds ee
// and all f16 error into the margin; r3..r16-proven). curmax = max(published
// per-row max read/atomicMax, local wave max) — any value <= true global
// max16 only loosens the threshold, correctness unchanged.
#define THR 2.048f
// candidate entry: high 19 bits = float bits of (score+512) with low 13
// mantissa bits zeroed (quant err <= 0.5; clamped positive -> bit-monotone);
// low 13 bits = k. finish prunes at (global best - 2.6): winner needs
// 0.98 (proven slack) + 0.5 (quant) = 1.48 -> 2.6 safe. [r11..r16-proven]
#define SCORE_OFS 512.0f
#define PRUNE_MARGIN 2.6f

__device__ __forceinline__ void gl_lds16(const void* g, void* l) {
    __builtin_amdgcn_global_load_lds(
        (const __attribute__((address_space(1))) unsigned int*)g,
        (__attribute__((address_space(3))) unsigned int*)l, 16, 0, 0);
}

// ---------------------------------------------------------------------------
// prep2: fused norms + f16 conversion, one pass over Z and E (r13-proven).
// ---------------------------------------------------------------------------
__device__ __forceinline__ float blk128_sq_cvt(const float* __restrict__ p,
                                               _Float16* __restrict__ o, float scale) {
    const float4* a4 = (const float4*)p;
    float4 v0 = a4[0], v1 = a4[1];
    float r[8];
    r[0] = __fmul_rn(v0.x, v0.x); r[1] = __fmul_rn(v0.y, v0.y);
    r[2] = __fmul_rn(v0.z, v0.z); r[3] = __fmul_rn(v0.w, v0.w);
    r[4] = __fmul_rn(v1.x, v1.x); r[5] = __fmul_rn(v1.y, v1.y);
    r[6] = __fmul_rn(v1.z, v1.z); r[7] = __fmul_rn(v1.w, v1.w);
    {
        f16x8 h;
        h[0] = (_Float16)(v0.x * scale); h[1] = (_Float16)(v0.y * scale);
        h[2] = (_Float16)(v0.z * scale); h[3] = (_Float16)(v0.w * scale);
        h[4] = (_Float16)(v1.x * scale); h[5] = (_Float16)(v1.y * scale);
        h[6] = (_Float16)(v1.z * scale); h[7] = (_Float16)(v1.w * scale);
        *(f16x8*)o = h;
    }
#pragma unroll
    for (int i = 1; i < 16; ++i) {
        v0 = a4[i * 2]; v1 = a4[i * 2 + 1];
        r[0] = __fadd_rn(r[0], __fmul_rn(v0.x, v0.x));
        r[1] = __fadd_rn(r[1], __fmul_rn(v0.y, v0.y));
        r[2] = __fadd_rn(r[2], __fmul_rn(v0.z, v0.z));
        r[3] = __fadd_rn(r[3], __fmul_rn(v0.w, v0.w));
        r[4] = __fadd_rn(r[4], __fmul_rn(v1.x, v1.x));
        r[5] = __fadd_rn(r[5], __fmul_rn(v1.y, v1.y));
        r[6] = __fadd_rn(r[6], __fmul_rn(v1.z, v1.z));
        r[7] = __fadd_rn(r[7], __fmul_rn(v1.w, v1.w));
        f16x8 h;
        h[0] = (_Float16)(v0.x * scale); h[1] = (_Float16)(v0.y * scale);
        h[2] = (_Float16)(v0.z * scale); h[3] = (_Float16)(v0.w * scale);
        h[4] = (_Float16)(v1.x * scale); h[5] = (_Float16)(v1.y * scale);
        h[6] = (_Float16)(v1.z * scale); h[7] = (_Float16)(v1.w * scale);
        *(f16x8*)(o + i * 8) = h;
    }
    return __fadd_rn(__fadd_rn(__fadd_rn(r[0], r[1]), __fadd_rn(r[2], r[3])),
                     __fadd_rn(__fadd_rn(r[4], r[5]), __fadd_rn(r[6], r[7])));
}

__global__ __launch_bounds__(256)
void prep2_kernel(const float* __restrict__ Z, const float* __restrict__ E,
                  _Float16* __restrict__ Zh, _Float16* __restrict__ Eh,
                  float* __restrict__ zz, float* __restrict__ ee,
                  unsigned int* __restrict__ cnt, unsigned int* __restrict__ rowmax,
                  double* __restrict__ lossAcc) {
    const int id = blockIdx.x * 256 + threadIdx.x;   // (NROWS+KCB)*4 total
    const int row = id >> 2, b = id & 3;
    if (id == 0) *lossAcc = 0.0;
    float blk;
    if (row < NROWS) {
        blk = blk128_sq_cvt(Z + (size_t)row * DIM + b * 128,
                            Zh + (size_t)row * DIM + b * 128, 1.0f);
    } else {
        const int k = row - NROWS;
        blk = blk128_sq_cvt(E + (size_t)k * DIM + b * 128,
                            Eh + (size_t)k * DIM + b * 128, 8192.0f);
    }
    float v1 = __fadd_rn(blk, __shfl_xor(blk, 1, 64));
    float v2 = __fadd_rn(v1, __shfl_xor(v1, 2, 64));
    if (b == 0) {
        if (row < NROWS) { zz[row] = v2; cnt[row] = 0; rowmax[row] = 0u; }
        else             ee[row - NROWS] = v2;
    }
}

// ---------------------------------------------------------------------------
// Screen v17 — r16 body (2-phase dbuf, (256,4), 501->474 proven) + two
// low-risk deltas:
//  (1) load-before-atomic on rowmax: leader lane plain-loads the published
//      row max and only atomicMax-publishes when its local max exceeds it.
//      rowmax is monotone; a stale/lower curmax only loosens the threshold
//      (superset of candidates) — correctness invariant unchanged. Cuts the
//      ~4.2M contended L2 atomics ~8-10x.
//  (2) T5 s_setprio(1) around the MFMA cluster: 4 resident blocks run at
//      different phases (not lockstep), the regime where setprio pays.
// ---------------------------------------------------------------------------
__global__ __launch_bounds__(256, 4)
void screen_kernel(const _Float16* __restrict__ Zh, const _Float16* __restrict__ Eh,
                   unsigned int* __restrict__ cnt, unsigned int* __restrict__ cand,
                   unsigned int* __restrict__ rowmax, const int cap) {
    __shared__ __align__(16) char lds[2 * 16384];   // 2 x (A 8 KiB + B 8 KiB)

    const int tid = threadIdx.x;
    const int l = tid & 63;
    const int w = tid >> 6;           // wave 0..3
    const int wrow = w >> 1;          // 0..1
    const int wcol = w & 1;           // 0..1
    const int rowBase = (int)(blockIdx.x & 255) * 128;
    const int colBase = (int)(blockIdx.x >> 8) * 128;

    // per-thread staging constants (r12/r16 verbatim + buffer base)
#define STAGE(ks, base) do {                                                   \
        _Pragma("unroll")                                                      \
        for (int _i = 0; _i < 2; ++_i) {                                       \
            const int _u = tid + _i * 256;                                     \
            const int _r = _u >> 2;                                            \
            const int _s = (_u & 3) ^ ((_r >> 1) & 3);                         \
            gl_lds16(Zh + (size_t)(rowBase + _r) * DIM + (ks) * 32 + _s * 8,   \
                     lds + (base) + (w * 64 + _i * 256) * 16 + l * 16);        \
            gl_lds16(Eh + (size_t)(colBase + _r) * DIM + (ks) * 32 + _s * 8,   \
                     lds + (base) + 8192 + (w * 64 + _i * 256) * 16 + l * 16); \
        }                                                                      \
    } while (0)

    // frag byte offsets (step-invariant; r6/r12 algebra, 0-conflict)
    int offA[4], offB[4];
#pragma unroll
    for (int m = 0; m < 4; ++m) {
        const int rr = wrow * 64 + m * 16 + (l & 15);
        offA[m] = (rr * 4 + ((l >> 4) ^ ((rr >> 1) & 3))) * 16;
    }
#pragma unroll
    for (int n = 0; n < 4; ++n) {
        const int c = wcol * 64 + n * 16 + (l & 15);
        offB[n] = 8192 + (c * 4 + ((l >> 4) ^ ((c >> 1) & 3))) * 16;
    }

    f32x4 acc[4][4];
#pragma unroll
    for (int m = 0; m < 4; ++m)
#pragma unroll
        for (int n = 0; n < 4; ++n) acc[m][n] = (f32x4){0.f, 0.f, 0.f, 0.f};

    // 2-phase K-loop: prologue fill buf0, then {stage-next | compute-cur}
    STAGE(0, 0);
    __syncthreads();                       // buf0 complete
    for (int ks = 0; ks < 16; ++ks) {
        const int cur = (ks & 1) * 16384;
        if (ks < 15) STAGE(ks + 1, 16384 - cur);   // fill other buffer, no wait
        const char* B = lds + cur;
        f16x8 af[4], bf[4];
#pragma unroll
        for (int m = 0; m < 4; ++m) af[m] = *(const f16x8*)(B + offA[m]);
#pragma unroll
        for (int n = 0; n < 4; ++n) bf[n] = *(const f16x8*)(B + offB[n]);
        __builtin_amdgcn_s_setprio(1);
#pragma unroll
        for (int m = 0; m < 4; ++m)
#pragma unroll
            for (int n = 0; n < 4; ++n)
                acc[m][n] = __builtin_amdgcn_mfma_f32_16x16x32_f16(af[m], bf[n], acc[m][n], 0, 0, 0);
        __builtin_amdgcn_s_setprio(0);
        if (ks < 15) __syncthreads();      // next buffer ready; my reads retired
    }

    // epilogue: shared-rowmax screen (load-before-atomic) + packed append
#pragma unroll
    for (int m = 0; m < 4; ++m) {
#pragma unroll
        for (int r = 0; r < 4; ++r) {
            float mx = fmaxf(fmaxf(acc[m][0][r], acc[m][1][r]),
                             fmaxf(acc[m][2][r], acc[m][3][r]));
#pragma unroll
            for (int off = 1; off < 16; off <<= 1)
                mx = fmaxf(mx, __shfl_xor(mx, off, 64));
            const int rowg = rowBase + wrow * 64 + m * 16 + (l >> 4) * 4 + r;
            const unsigned mxbits = __float_as_uint(fmaxf(mx, -256.0f) + SCORE_OFS);
            unsigned curbits = 0;
            if ((l & 15) == 0) {
                curbits = rowmax[rowg];               // published max (monotone)
                if (mxbits > curbits)
                    atomicMax(&rowmax[rowg], mxbits); // publish only if we beat it
            }
            curbits = __shfl(curbits, l & 48, 64);    // broadcast leader's load
            const float cur = fmaxf(__uint_as_float(curbits < mxbits ? mxbits : curbits),
                                    __uint_as_float(mxbits));
            const float thr = cur - SCORE_OFS - THR;
#pragma unroll
            for (int n = 0; n < 4; ++n) {
                if (acc[m][n][r] >= thr) {
                    unsigned pos = atomicAdd(&cnt[rowg], 1u);
                    if (pos < (unsigned)cap) {
                        unsigned kidx = (unsigned)(colBase + wcol * 64 + n * 16 + (l & 15));
                        float sc = fmaxf(acc[m][n][r] + SCORE_OFS, 1.0f);
                        cand[(size_t)rowg * cap + pos] =
                            (__float_as_uint(sc) & 0xFFFFE000u) | kidx;
                    }
                }
            }
        }
    }
#undef STAGE
}

// ---------------------------------------------------------------------------
// finish: prune via packed scores, exact rescore (bit-identical chain),
// gather + loss. c > cap or c == 0 -> exact full 8192-code scan.
// [r10..r16-proven, verbatim]
// ---------------------------------------------------------------------------
__global__ __launch_bounds__(256)
void finish_kernel(const float* __restrict__ Z, const float* __restrict__ E,
                   const float* __restrict__ zz, const float* __restrict__ ee,
                   const unsigned int* __restrict__ cnt,
                   const unsigned int* __restrict__ cand,
                   float* __restrict__ outZ, float* __restrict__ outIdxF,
                   double* __restrict__ lossAcc, const int cap) {
    __shared__ double psum[4];
    const int tid = threadIdx.x;
    const int l = tid & 63;
    const int w = tid >> 6;
    double s = 0.0;

    for (int j = 0; j < 8; ++j) {
        const int row = blockIdx.x * 32 + w * 8 + j;
        const unsigned c = cnt[row];
        int kk;
        if (c == 1) {
            kk = (int)(cand[(size_t)row * cap] & 0x1FFFu);
        } else if (c >= 2 && c <= (unsigned)cap) {
            const unsigned key1 = (l < (int)c) ? cand[(size_t)row * cap + l] : 0u;
            const unsigned key2 = ((int)c > 64 && l + 64 < (int)c)
                                      ? cand[(size_t)row * cap + l + 64] : 0u;
            const float s1 = __uint_as_float(key1 & 0xFFFFE000u);
            const float s2 = __uint_as_float(key2 & 0xFFFFE000u);
            float smax = fmaxf(s1, s2);
#pragma unroll
            for (int off = 1; off < 64; off <<= 1)
                smax = fmaxf(smax, __shfl_xor(smax, off, 64));
            const float cut = smax - PRUNE_MARGIN;

            float d2 = __builtin_inff();
            int kl = 0x7FFFFFFF;
            const float4* zr4 = (const float4*)(Z + (size_t)row * DIM);
            if (l < (int)c && s1 >= cut) {
                int k = (int)(key1 & 0x1FFFu);
                const float4* er4 = (const float4*)(E + (size_t)k * DIM);
                float acc = 0.0f;
#pragma unroll 8
                for (int i = 0; i < DIM / 4; ++i) {
                    float4 z4 = zr4[i], e4 = er4[i];
                    acc = __builtin_fmaf(z4.x, e4.x, acc);
                    acc = __builtin_fmaf(z4.y, e4.y, acc);
                    acc = __builtin_fmaf(z4.z, e4.z, acc);
                    acc = __builtin_fmaf(z4.w, e4.w, acc);
                }
                float t = __builtin_fmaf(-2.0f, acc, zz[row]);
                d2 = __fadd_rn(t, ee[k]);
                kl = k;
            }
            if ((int)c > 64 && l + 64 < (int)c && s2 >= cut) {
                int k = (int)(key2 & 0x1FFFu);
                const float4* er4 = (const float4*)(E + (size_t)k * DIM);
                float acc = 0.0f;
#pragma unroll 8
                for (int i = 0; i < DIM / 4; ++i) {
                    float4 z4 = zr4[i], e4 = er4[i];
                    acc = __builtin_fmaf(z4.x, e4.x, acc);
                    acc = __builtin_fmaf(z4.y, e4.y, acc);
                    acc = __builtin_fmaf(z4.z, e4.z, acc);
                    acc = __builtin_fmaf(z4.w, e4.w, acc);
                }
                float t = __builtin_fmaf(-2.0f, acc, zz[row]);
                float d = __fadd_rn(t, ee[k]);
                if (d < d2 || (d == d2 && k < kl)) { d2 = d; kl = k; }
            }
#pragma unroll
            for (int off = 32; off > 0; off >>= 1) {
                float od = __shfl_down(d2, off, 64);
                int ok = __shfl_down(kl, off, 64);
                if (od < d2 || (od == d2 && ok < kl)) { d2 = od; kl = ok; }
            }
            kk = __shfl(kl, 0, 64);
        } else {
            // overflow (c > cap) or degenerate (c == 0): exact full scan
            float d2 = __builtin_inff();
            int kl = 0x7FFFFFFF;
            const float4* zr4 = (const float4*)(Z + (size_t)row * DIM);
            for (int k = l; k < KCB; k += 64) {
                const float4* er4 = (const float4*)(E + (size_t)k * DIM);
                float acc = 0.0f;
#pragma unroll 8
                for (int i = 0; i < DIM / 4; ++i) {
                    float4 z4 = zr4[i], e4 = er4[i];
                    acc = __builtin_fmaf(z4.x, e4.x, acc);
                    acc = __builtin_fmaf(z4.y, e4.y, acc);
                    acc = __builtin_fmaf(z4.z, e4.z, acc);
                    acc = __builtin_fmaf(z4.w, e4.w, acc);
                }
                float t = __builtin_fmaf(-2.0f, acc, zz[row]);
                float d = __fadd_rn(t, ee[k]);
                if (d < d2) { d2 = d; kl = k; }   // per-lane k ascending
            }
#pragma unroll
            for (int off = 32; off > 0; off >>= 1) {
                float od = __shfl_down(d2, off, 64);
                int ok = __shfl_down(kl, off, 64);
                if (od < d2 || (od == d2 && ok < kl)) { d2 = od; kl = ok; }
            }
            kk = __shfl(kl, 0, 64);
        }
        const float* zr = Z + (size_t)row * DIM;
        const float* er = E + (size_t)kk * DIM;
        float* orow = outZ + (size_t)row * DIM;
#pragma unroll
        for (int i = 0; i < 2; ++i) {
            int off = (l + i * 64) * 4;
            float4 z4 = *(const float4*)(zr + off);
            float4 e4 = *(const float4*)(er + off);
            float dx = __fsub_rn(e4.x, z4.x);
            float dy = __fsub_rn(e4.y, z4.y);
            float dz = __fsub_rn(e4.z, z4.z);
            float dw = __fsub_rn(e4.w, z4.w);
            float4 st;
            st.x = __fadd_rn(z4.x, dx);
            st.y = __fadd_rn(z4.y, dy);
            st.z = __fadd_rn(z4.z, dz);
            st.w = __fadd_rn(z4.w, dw);
            *(float4*)(orow + off) = st;
            s += (double)dx * dx + (double)dy * dy + (double)dz * dz + (double)dw * dw;
        }
        if (l == 0) outIdxF[row] = (float)kk;
    }
#pragma unroll
    for (int o = 32; o > 0; o >>= 1) s += __shfl_down(s, o, 64);
    if (l == 0) psum[w] = s;
    __syncthreads();
    if (tid == 0)
        atomicAdd(lossAcc, psum[0] + psum[1] + psum[2] + psum[3]);
}

__global__ void finalize_kernel(const double* __restrict__ lossAcc,
                                float* __restrict__ outLoss) {
    double m = *lossAcc / (double)((size_t)NROWS * DIM);
    float mf = (float)m;
    float c = __fmul_rn(0.25f, mf);
    *outLoss = __fadd_rn(c, mf);
}

// ---------------------------------------------------------------------------
// Fallback (ws too small): round-1 proven-correct VALU path, verbatim.
// ---------------------------------------------------------------------------
__device__ __forceinline__ float pairwise512_sq(const float* __restrict__ p) {
    float blk[4];
#pragma unroll
    for (int b = 0; b < 4; ++b) {
        const float* a = p + b * 128;
        float r[8];
#pragma unroll
        for (int j = 0; j < 8; ++j) r[j] = __fmul_rn(a[j], a[j]);
#pragma unroll
        for (int i = 8; i < 128; i += 8) {
#pragma unroll
            for (int j = 0; j < 8; ++j)
                r[j] = __fadd_rn(r[j], __fmul_rn(a[i + j], a[i + j]));
        }
        blk[b] = __fadd_rn(__fadd_rn(__fadd_rn(r[0], r[1]), __fadd_rn(r[2], r[3])),
                           __fadd_rn(__fadd_rn(r[4], r[5]), __fadd_rn(r[6], r[7])));
    }
    return __fadd_rn(__fadd_rn(blk[0], blk[1]), __fadd_rn(blk[2], blk[3]));
}

__global__ void ee_kernel(const float* __restrict__ E, float* __restrict__ ee) {
    int k = blockIdx.x * blockDim.x + threadIdx.x;
    if (k < KCB) ee[k] = pairwise512_sq(E + (size_t)k * DIM);
}

__global__ __launch_bounds__(512, 2)
void argmin_fallback(const float* __restrict__ Z, const float* __restrict__ E,
                     const float* __restrict__ ee, int* __restrict__ outIdx) {
    __shared__ __align__(16) char smem[(32 * 132 + 32 * 260) * 4];
    float (*As)[132] = (float (*)[132])smem;
    float (*Bs)[260] = (float (*)[260])(smem + 32 * 132 * 4);
    __shared__ float zzs[128];
    const int tid = threadIdx.x;
    const int tx = tid & 31;
    const int ty = tid >> 5;
    const int rowBase = blockIdx.x * 128;
    if (tid < 128) zzs[tid] = pairwise512_sq(Z + (size_t)(rowBase + tid) * DIM);
    __syncthreads();
    float zz[8];
#pragma unroll
    for (int m = 0; m < 8; ++m) zz[m] = zzs[ty * 8 + m];
    float bestV[8]; int bestI[8];
#pragma unroll
    for (int m = 0; m < 8; ++m) { bestV[m] = __builtin_inff(); bestI[m] = 0; }
    for (int tile = 0; tile < 32; ++tile) {
        float acc[8][8];
#pragma unroll
        for (int m = 0; m < 8; ++m)
#pragma unroll
            for (int n = 0; n < 8; ++n) acc[m][n] = 0.0f;
        for (int kc = 0; kc < DIM; kc += 32) {
            __syncthreads();
#pragma unroll
            for (int i = 0; i < 2; ++i) {
                int id4 = tid + i * 512;
                int r = id4 >> 3, c = id4 & 7;
                float4 v = *(const float4*)(Z + (size_t)(rowBase + r) * DIM + kc + c * 4);
                As[c * 4 + 0][r] = v.x; As[c * 4 + 1][r] = v.y;
                As[c * 4 + 2][r] = v.z; As[c * 4 + 3][r] = v.w;
            }
#pragma unroll
            for (int i = 0; i < 4; ++i) {
                int id4 = tid + i * 512;
                int r = id4 >> 3, c = id4 & 7;
                float4 v = *(const float4*)(E + (size_t)(tile * 256 + r) * DIM + kc + c * 4);
                Bs[c * 4 + 0][r] = v.x; Bs[c * 4 + 1][r] = v.y;
                Bs[c * 4 + 2][r] = v.z; Bs[c * 4 + 3][r] = v.w;
            }
            __syncthreads();
#pragma unroll
            for (int kk = 0; kk < 32; ++kk) {
                float a[8], b[8];
                *(float4*)&a[0] = *(const float4*)&As[kk][ty * 8];
                *(float4*)&a[4] = *(const float4*)&As[kk][ty * 8 + 4];
                *(float4*)&b[0] = *(const float4*)&Bs[kk][tx * 8];
                *(float4*)&b[4] = *(const float4*)&Bs[kk][tx * 8 + 4];
#pragma unroll
                for (int m = 0; m < 8; ++m)
#pragma unroll
                    for (int n = 0; n < 8; ++n)
                        acc[m][n] = __builtin_fmaf(a[m], b[n], acc[m][n]);
            }
        }
#pragma unroll
        for (int m = 0; m < 8; ++m) {
#pragma unroll
            for (int n = 0; n < 8; ++n) {
                float t = __builtin_fmaf(-2.0f, acc[m][n], zz[m]);
                float d2 = __fadd_rn(t, ee[tile * 256 + tx * 8 + n]);
                int kidx = tile * 256 + tx * 8 + n;
                if (d2 < bestV[m]) { bestV[m] = d2; bestI[m] = kidx; }
            }
        }
    }
    __syncthreads();
    float (*redV)[33] = (float (*)[33])smem;
    int   (*redI)[33] = (int (*)[33])(smem + 128 * 33 * 4);
#pragma unroll
    for (int m = 0; m < 8; ++m) {
        redV[ty * 8 + m][tx] = bestV[m];
        redI[ty * 8 + m][tx] = bestI[m];
    }
    __syncthreads();
    if (tid < 128) {
        float bv = redV[tid][0]; int bi = redI[tid][0];
        for (int j = 1; j < 32; ++j) {
            float v = redV[tid][j]; int ii = redI[tid][j];
            if (v < bv || (v == bv && ii < bi)) { bv = v; bi = ii; }
        }
        outIdx[rowBase + tid] = bi;
    }
}

__global__ void gather_kernel(const float* __restrict__ Z, const float* __restrict__ E,
                              const int* __restrict__ idx, float* __restrict__ outZ,
                              float* __restrict__ outIdxF, double* __restrict__ lossAcc) {
    int row = blockIdx.x;
    int t = threadIdx.x;  // 64
    int k = idx[row];
    const float* zr = Z + (size_t)row * DIM;
    const float* er = E + (size_t)k * DIM;
    float* orow = outZ + (size_t)row * DIM;
    double s = 0.0;
#pragma unroll
    for (int i = 0; i < 2; ++i) {
        int off = (t + i * 64) * 4;
        float4 z4 = *(const float4*)(zr + off);
        float4 e4 = *(const float4*)(er + off);
        float dx = __fsub_rn(e4.x, z4.x);
        float dy = __fsub_rn(e4.y, z4.y);
        float dz = __fsub_rn(e4.z, z4.z);
        float dw = __fsub_rn(e4.w, z4.w);
        float4 st;
        st.x = __fadd_rn(z4.x, dx);
        st.y = __fadd_rn(z4.y, dy);
        st.z = __fadd_rn(z4.z, dz);
        st.w = __fadd_rn(z4.w, dw);
        *(float4*)(orow + off) = st;
        s += (double)dx * dx + (double)dy * dy + (double)dz * dz + (double)dw * dw;
    }
#pragma unroll
    for (int o = 32; o > 0; o >>= 1) s += __shfl_down(s, o, 64);
    if (t == 0) {
        atomicAdd(lossAcc, s);
        outIdxF[row] = (float)k;
    }
}

// ---------------------------------------------------------------------------
extern "C" void kernel_launch(void* const* d_in, const int* in_sizes, int n_in,
                              void* d_out, int out_size, void* d_ws, size_t ws_size,
                              hipStream_t stream) {
    const float* Z = (const float*)d_in[0];
    const float* E = (const float*)d_in[1];
    float* out = (float*)d_out;
    float* zq_out = out;
    float* loss_out = out + (size_t)NROWS * DIM;
    float* idxf_out = loss_out + 1;

    if (ws_size >= WS_NEEDED_64) {
        const int cap = (ws_size >= WS_NEEDED_128) ? 128 : 64;
        _Float16* Zh = (_Float16*)((char*)d_ws + OFF_ZH);
        _Float16* Eh = (_Float16*)((char*)d_ws + OFF_EH);
        float* ee = (float*)((char*)d_ws + OFF_EE);
        float* zz = (float*)((char*)d_ws + OFF_ZZ);
        unsigned int* cnt = (unsigned int*)((char*)d_ws + OFF_CNT);
        unsigned int* cand = (unsigned int*)((char*)d_ws + OFF_CAND);
        unsigned int* rowmax = (unsigned int*)((char*)d_ws + OFF_CAND
                                               + (size_t)NROWS * cap * 4);
        double* lossAcc = (double*)((char*)d_ws + OFF_LOSS);

        prep2_kernel<<<(NROWS + KCB) * 4 / 256, 256, 0, stream>>>(Z, E, Zh, Eh, zz, ee,
                                                                  cnt, rowmax, lossAcc);
        screen_kernel<<<256 * 64, 256, 0, stream>>>(Zh, Eh, cnt, cand, rowmax, cap);
        finish_kernel<<<NROWS / 32, 256, 0, stream>>>(Z, E, zz, ee, cnt, cand,
                                                      zq_out, idxf_out, lossAcc, cap);
        finalize_kernel<<<1, 1, 0, stream>>>(lossAcc, loss_out);
    } else {
        float* ee = (float*)d_ws;
        int* idx = (int*)((char*)d_ws + 32768);
        double* lossAcc = (double*)((char*)d_ws + 163840);
        hipMemsetAsync(lossAcc, 0, sizeof(double), stream);
        ee_kernel<<<KCB / 256, 256, 0, stream>>>(E, ee);
        argmin_fallback<<<NROWS / 128, 512, 0, stream>>>(Z, E, ee, idx);
        gather_kernel<<<NROWS, 64, 0, stream>>>(Z, E, idx, zq_out, idxf_out, lossAcc);
        finalize_kernel<<<1, 1, 0, stream>>>(lossAcc, loss_out);
    }
}

// Round 18
// 703.837 us; speedup vs baseline: 3.5183x; 1.0200x over previous
//
#include <hip/hip_runtime.h>
#include <math.h>

#define DIM    512
#define KCB    8192
#define NROWS  32768

typedef _Float16 f16x8 __attribute__((ext_vector_type(8)));
typedef float    f32x4 __attribute__((ext_vector_type(4)));

// ---- workspace layout (main path) ----
#define OFF_ZH    0ull                    // f16 Z  [32768][512] = 33554432 B
#define OFF_EH    33554432ull             // f16 E*8192 [8192][512] = 8388608 B
#define OFF_EE    41943040ull             // f32 ee [8192]
#define OFF_ZZ    41975808ull             // f32 zz [32768]
#define OFF_CNT   42106880ull             // u32 cnt[32768]
#define OFF_LOSS  42237952ull             // f64 loss accumulator
#define OFF_CAND  42237960ull             // u32 cand[32768][cap] (packed score|idx)
// rowmax u32[32768] follows cand; sizes:
#define WS_NEEDED_64  50757640ull         // cap = 64  (cand 8 MB + rowmax 128 KB)
#define WS_NEEDED_128 59146248ull         // cap = 128 (cand 16 MB + rowmax 128 KB)
// screen keeps k if dot16_scaled >= curmax - THR (E scaled by 2^13; folds ee
// and all f16 error into the margin; r3..r17-proven). curmax = max(published
// per-row max read/atomicMax, local wave max) — any value <= true global
// max16 only loosens the threshold, correctness unchanged.
#define THR 2.048f
// candidate entry: high 19 bits = float bits of (score+512) with low 13
// mantissa bits zeroed (quant err <= 0.5; clamped positive -> bit-monotone);
// low 13 bits = k. finish prunes at (global best - 2.6): winner needs
// 0.98 (proven slack) + 0.5 (quant) = 1.48 -> 2.6 safe. [r11..r17-proven]
#define SCORE_OFS 512.0f
#define PRUNE_MARGIN 2.6f

__device__ __forceinline__ void gl_lds16(const void* g, void* l) {
    __builtin_amdgcn_global_load_lds(
        (const __attribute__((address_space(1))) unsigned int*)g,
        (__attribute__((address_space(3))) unsigned int*)l, 16, 0, 0);
}

// ---------------------------------------------------------------------------
// prep2: fused norms + f16 conversion, one pass over Z and E (r13-proven).
// ---------------------------------------------------------------------------
__device__ __forceinline__ float blk128_sq_cvt(const float* __restrict__ p,
                                               _Float16* __restrict__ o, float scale) {
    const float4* a4 = (const float4*)p;
    float4 v0 = a4[0], v1 = a4[1];
    float r[8];
    r[0] = __fmul_rn(v0.x, v0.x); r[1] = __fmul_rn(v0.y, v0.y);
    r[2] = __fmul_rn(v0.z, v0.z); r[3] = __fmul_rn(v0.w, v0.w);
    r[4] = __fmul_rn(v1.x, v1.x); r[5] = __fmul_rn(v1.y, v1.y);
    r[6] = __fmul_rn(v1.z, v1.z); r[7] = __fmul_rn(v1.w, v1.w);
    {
        f16x8 h;
        h[0] = (_Float16)(v0.x * scale); h[1] = (_Float16)(v0.y * scale);
        h[2] = (_Float16)(v0.z * scale); h[3] = (_Float16)(v0.w * scale);
        h[4] = (_Float16)(v1.x * scale); h[5] = (_Float16)(v1.y * scale);
        h[6] = (_Float16)(v1.z * scale); h[7] = (_Float16)(v1.w * scale);
        *(f16x8*)o = h;
    }
#pragma unroll
    for (int i = 1; i < 16; ++i) {
        v0 = a4[i * 2]; v1 = a4[i * 2 + 1];
        r[0] = __fadd_rn(r[0], __fmul_rn(v0.x, v0.x));
        r[1] = __fadd_rn(r[1], __fmul_rn(v0.y, v0.y));
        r[2] = __fadd_rn(r[2], __fmul_rn(v0.z, v0.z));
        r[3] = __fadd_rn(r[3], __fmul_rn(v0.w, v0.w));
        r[4] = __fadd_rn(r[4], __fmul_rn(v1.x, v1.x));
        r[5] = __fadd_rn(r[5], __fmul_rn(v1.y, v1.y));
        r[6] = __fadd_rn(r[6], __fmul_rn(v1.z, v1.z));
        r[7] = __fadd_rn(r[7], __fmul_rn(v1.w, v1.w));
        f16x8 h;
        h[0] = (_Float16)(v0.x * scale); h[1] = (_Float16)(v0.y * scale);
        h[2] = (_Float16)(v0.z * scale); h[3] = (_Float16)(v0.w * scale);
        h[4] = (_Float16)(v1.x * scale); h[5] = (_Float16)(v1.y * scale);
        h[6] = (_Float16)(v1.z * scale); h[7] = (_Float16)(v1.w * scale);
        *(f16x8*)(o + i * 8) = h;
    }
    return __fadd_rn(__fadd_rn(__fadd_rn(r[0], r[1]), __fadd_rn(r[2], r[3])),
                     __fadd_rn(__fadd_rn(r[4], r[5]), __fadd_rn(r[6], r[7])));
}

__global__ __launch_bounds__(256)
void prep2_kernel(const float* __restrict__ Z, const float* __restrict__ E,
                  _Float16* __restrict__ Zh, _Float16* __restrict__ Eh,
                  float* __restrict__ zz, float* __restrict__ ee,
                  unsigned int* __restrict__ cnt, unsigned int* __restrict__ rowmax,
                  double* __restrict__ lossAcc) {
    const int id = blockIdx.x * 256 + threadIdx.x;   // (NROWS+KCB)*4 total
    const int row = id >> 2, b = id & 3;
    if (id == 0) *lossAcc = 0.0;
    float blk;
    if (row < NROWS) {
        blk = blk128_sq_cvt(Z + (size_t)row * DIM + b * 128,
                            Zh + (size_t)row * DIM + b * 128, 1.0f);
    } else {
        const int k = row - NROWS;
        blk = blk128_sq_cvt(E + (size_t)k * DIM + b * 128,
                            Eh + (size_t)k * DIM + b * 128, 8192.0f);
    }
    float v1 = __fadd_rn(blk, __shfl_xor(blk, 1, 64));
    float v2 = __fadd_rn(v1, __shfl_xor(v1, 2, 64));
    if (b == 0) {
        if (row < NROWS) { zz[row] = v2; cnt[row] = 0; rowmax[row] = 0u; }
        else             ee[row - NROWS] = v2;
    }
}

// ---------------------------------------------------------------------------
// Screen v17 (FROZEN — 444 µs proven): r16 2-phase dbuf + load-before-atomic
// rowmax + setprio around MFMA. (256,4): unified VGPR+AGPR footprint is
// exactly 128/thread; higher waves/EU caps spill (r13/r15).
// ---------------------------------------------------------------------------
__global__ __launch_bounds__(256, 4)
void screen_kernel(const _Float16* __restrict__ Zh, const _Float16* __restrict__ Eh,
                   unsigned int* __restrict__ cnt, unsigned int* __restrict__ cand,
                   unsigned int* __restrict__ rowmax, const int cap) {
    __shared__ __align__(16) char lds[2 * 16384];   // 2 x (A 8 KiB + B 8 KiB)

    const int tid = threadIdx.x;
    const int l = tid & 63;
    const int w = tid >> 6;           // wave 0..3
    const int wrow = w >> 1;          // 0..1
    const int wcol = w & 1;           // 0..1
    const int rowBase = (int)(blockIdx.x & 255) * 128;
    const int colBase = (int)(blockIdx.x >> 8) * 128;

#define STAGE(ks, base) do {                                                   \
        _Pragma("unroll")                                                      \
        for (int _i = 0; _i < 2; ++_i) {                                       \
            const int _u = tid + _i * 256;                                     \
            const int _r = _u >> 2;                                            \
            const int _s = (_u & 3) ^ ((_r >> 1) & 3);                         \
            gl_lds16(Zh + (size_t)(rowBase + _r) * DIM + (ks) * 32 + _s * 8,   \
                     lds + (base) + (w * 64 + _i * 256) * 16 + l * 16);        \
            gl_lds16(Eh + (size_t)(colBase + _r) * DIM + (ks) * 32 + _s * 8,   \
                     lds + (base) + 8192 + (w * 64 + _i * 256) * 16 + l * 16); \
        }                                                                      \
    } while (0)

    int offA[4], offB[4];
#pragma unroll
    for (int m = 0; m < 4; ++m) {
        const int rr = wrow * 64 + m * 16 + (l & 15);
        offA[m] = (rr * 4 + ((l >> 4) ^ ((rr >> 1) & 3))) * 16;
    }
#pragma unroll
    for (int n = 0; n < 4; ++n) {
        const int c = wcol * 64 + n * 16 + (l & 15);
        offB[n] = 8192 + (c * 4 + ((l >> 4) ^ ((c >> 1) & 3))) * 16;
    }

    f32x4 acc[4][4];
#pragma unroll
    for (int m = 0; m < 4; ++m)
#pragma unroll
        for (int n = 0; n < 4; ++n) acc[m][n] = (f32x4){0.f, 0.f, 0.f, 0.f};

    STAGE(0, 0);
    __syncthreads();                       // buf0 complete
    for (int ks = 0; ks < 16; ++ks) {
        const int cur = (ks & 1) * 16384;
        if (ks < 15) STAGE(ks + 1, 16384 - cur);   // fill other buffer, no wait
        const char* B = lds + cur;
        f16x8 af[4], bf[4];
#pragma unroll
        for (int m = 0; m < 4; ++m) af[m] = *(const f16x8*)(B + offA[m]);
#pragma unroll
        for (int n = 0; n < 4; ++n) bf[n] = *(const f16x8*)(B + offB[n]);
        __builtin_amdgcn_s_setprio(1);
#pragma unroll
        for (int m = 0; m < 4; ++m)
#pragma unroll
            for (int n = 0; n < 4; ++n)
                acc[m][n] = __builtin_amdgcn_mfma_f32_16x16x32_f16(af[m], bf[n], acc[m][n], 0, 0, 0);
        __builtin_amdgcn_s_setprio(0);
        if (ks < 15) __syncthreads();      // next buffer ready; my reads retired
    }

    // epilogue: shared-rowmax screen (load-before-atomic) + packed append
#pragma unroll
    for (int m = 0; m < 4; ++m) {
#pragma unroll
        for (int r = 0; r < 4; ++r) {
            float mx = fmaxf(fmaxf(acc[m][0][r], acc[m][1][r]),
                             fmaxf(acc[m][2][r], acc[m][3][r]));
#pragma unroll
            for (int off = 1; off < 16; off <<= 1)
                mx = fmaxf(mx, __shfl_xor(mx, off, 64));
            const int rowg = rowBase + wrow * 64 + m * 16 + (l >> 4) * 4 + r;
            const unsigned mxbits = __float_as_uint(fmaxf(mx, -256.0f) + SCORE_OFS);
            unsigned curbits = 0;
            if ((l & 15) == 0) {
                curbits = rowmax[rowg];               // published max (monotone)
                if (mxbits > curbits)
                    atomicMax(&rowmax[rowg], mxbits); // publish only if we beat it
            }
            curbits = __shfl(curbits, l & 48, 64);    // broadcast leader's load
            const float cur = fmaxf(__uint_as_float(curbits < mxbits ? mxbits : curbits),
                                    __uint_as_float(mxbits));
            const float thr = cur - SCORE_OFS - THR;
#pragma unroll
            for (int n = 0; n < 4; ++n) {
                if (acc[m][n][r] >= thr) {
                    unsigned pos = atomicAdd(&cnt[rowg], 1u);
                    if (pos < (unsigned)cap) {
                        unsigned kidx = (unsigned)(colBase + wcol * 64 + n * 16 + (l & 15));
                        float sc = fmaxf(acc[m][n][r] + SCORE_OFS, 1.0f);
                        cand[(size_t)rowg * cap + pos] =
                            (__float_as_uint(sc) & 0xFFFFE000u) | kidx;
                    }
                }
            }
        }
    }
#undef STAGE
}

// ---------------------------------------------------------------------------
// finish v2: r17 logic verbatim, 4x grid parallelism (4096 blocks, 8 rows
// per block, 2 rows per wave instead of 8) — the per-row dependent-load
// chain (cnt -> cand -> zz -> E-rows -> gather) is latency-bound; 4x TLP
// hides it. Numerics byte-identical.
// ---------------------------------------------------------------------------
__global__ __launch_bounds__(256)
void finish_kernel(const float* __restrict__ Z, const float* __restrict__ E,
                   const float* __restrict__ zz, const float* __restrict__ ee,
                   const unsigned int* __restrict__ cnt,
                   const unsigned int* __restrict__ cand,
                   float* __restrict__ outZ, float* __restrict__ outIdxF,
                   double* __restrict__ lossAcc, const int cap) {
    __shared__ double psum[4];
    const int tid = threadIdx.x;
    const int l = tid & 63;
    const int w = tid >> 6;
    double s = 0.0;

    for (int j = 0; j < 2; ++j) {
        const int row = blockIdx.x * 8 + w * 2 + j;
        const unsigned c = cnt[row];
        int kk;
        if (c == 1) {
            kk = (int)(cand[(size_t)row * cap] & 0x1FFFu);
        } else if (c >= 2 && c <= (unsigned)cap) {
            const unsigned key1 = (l < (int)c) ? cand[(size_t)row * cap + l] : 0u;
            const unsigned key2 = ((int)c > 64 && l + 64 < (int)c)
                                      ? cand[(size_t)row * cap + l + 64] : 0u;
            const float s1 = __uint_as_float(key1 & 0xFFFFE000u);
            const float s2 = __uint_as_float(key2 & 0xFFFFE000u);
            float smax = fmaxf(s1, s2);
#pragma unroll
            for (int off = 1; off < 64; off <<= 1)
                smax = fmaxf(smax, __shfl_xor(smax, off, 64));
            const float cut = smax - PRUNE_MARGIN;

            float d2 = __builtin_inff();
            int kl = 0x7FFFFFFF;
            const float4* zr4 = (const float4*)(Z + (size_t)row * DIM);
            if (l < (int)c && s1 >= cut) {
                int k = (int)(key1 & 0x1FFFu);
                const float4* er4 = (const float4*)(E + (size_t)k * DIM);
                float acc = 0.0f;
#pragma unroll 8
                for (int i = 0; i < DIM / 4; ++i) {
                    float4 z4 = zr4[i], e4 = er4[i];
                    acc = __builtin_fmaf(z4.x, e4.x, acc);
                    acc = __builtin_fmaf(z4.y, e4.y, acc);
                    acc = __builtin_fmaf(z4.z, e4.z, acc);
                    acc = __builtin_fmaf(z4.w, e4.w, acc);
                }
                float t = __builtin_fmaf(-2.0f, acc, zz[row]);
                d2 = __fadd_rn(t, ee[k]);
                kl = k;
            }
            if ((int)c > 64 && l + 64 < (int)c && s2 >= cut) {
                int k = (int)(key2 & 0x1FFFu);
                const float4* er4 = (const float4*)(E + (size_t)k * DIM);
                float acc = 0.0f;
#pragma unroll 8
                for (int i = 0; i < DIM / 4; ++i) {
                    float4 z4 = zr4[i], e4 = er4[i];
                    acc = __builtin_fmaf(z4.x, e4.x, acc);
                    acc = __builtin_fmaf(z4.y, e4.y, acc);
                    acc = __builtin_fmaf(z4.z, e4.z, acc);
                    acc = __builtin_fmaf(z4.w, e4.w, acc);
                }
                float t = __builtin_fmaf(-2.0f, acc, zz[row]);
                float d = __fadd_rn(t, ee[k]);
                if (d < d2 || (d == d2 && k < kl)) { d2 = d; kl = k; }
            }
#pragma unroll
            for (int off = 32; off > 0; off >>= 1) {
                float od = __shfl_down(d2, off, 64);
                int ok = __shfl_down(kl, off, 64);
                if (od < d2 || (od == d2 && ok < kl)) { d2 = od; kl = ok; }
            }
            kk = __shfl(kl, 0, 64);
        } else {
            // overflow (c > cap) or degenerate (c == 0): exact full scan
            float d2 = __builtin_inff();
            int kl = 0x7FFFFFFF;
            const float4* zr4 = (const float4*)(Z + (size_t)row * DIM);
            for (int k = l; k < KCB; k += 64) {
                const float4* er4 = (const float4*)(E + (size_t)k * DIM);
                float acc = 0.0f;
#pragma unroll 8
                for (int i = 0; i < DIM / 4; ++i) {
                    float4 z4 = zr4[i], e4 = er4[i];
                    acc = __builtin_fmaf(z4.x, e4.x, acc);
                    acc = __builtin_fmaf(z4.y, e4.y, acc);
                    acc = __builtin_fmaf(z4.z, e4.z, acc);
                    acc = __builtin_fmaf(z4.w, e4.w, acc);
                }
                float t = __builtin_fmaf(-2.0f, acc, zz[row]);
                float d = __fadd_rn(t, ee[k]);
                if (d < d2) { d2 = d; kl = k; }   // per-lane k ascending
            }
#pragma unroll
            for (int off = 32; off > 0; off >>= 1) {
                float od = __shfl_down(d2, off, 64);
                int ok = __shfl_down(kl, off, 64);
                if (od < d2 || (od == d2 && ok < kl)) { d2 = od; kl = ok; }
            }
            kk = __shfl(kl, 0, 64);
        }
        const float* zr = Z + (size_t)row * DIM;
        const float* er = E + (size_t)kk * DIM;
        float* orow = outZ + (size_t)row * DIM;
#pragma unroll
        for (int i = 0; i < 2; ++i) {
            int off = (l + i * 64) * 4;
            float4 z4 = *(const float4*)(zr + off);
            float4 e4 = *(const float4*)(er + off);
            float dx = __fsub_rn(e4.x, z4.x);
            float dy = __fsub_rn(e4.y, z4.y);
            float dz = __fsub_rn(e4.z, z4.z);
            float dw = __fsub_rn(e4.w, z4.w);
            float4 st;
            st.x = __fadd_rn(z4.x, dx);
            st.y = __fadd_rn(z4.y, dy);
            st.z = __fadd_rn(z4.z, dz);
            st.w = __fadd_rn(z4.w, dw);
            *(float4*)(orow + off) = st;
            s += (double)dx * dx + (double)dy * dy + (double)dz * dz + (double)dw * dw;
        }
        if (l == 0) outIdxF[row] = (float)kk;
    }
#pragma unroll
    for (int o = 32; o > 0; o >>= 1) s += __shfl_down(s, o, 64);
    if (l == 0) psum[w] = s;
    __syncthreads();
    if (tid == 0)
        atomicAdd(lossAcc, psum[0] + psum[1] + psum[2] + psum[3]);
}

__global__ void finalize_kernel(const double* __restrict__ lossAcc,
                                float* __restrict__ outLoss) {
    double m = *lossAcc / (double)((size_t)NROWS * DIM);
    float mf = (float)m;
    float c = __fmul_rn(0.25f, mf);
    *outLoss = __fadd_rn(c, mf);
}

// ---------------------------------------------------------------------------
// Fallback (ws too small): round-1 proven-correct VALU path, verbatim.
// ---------------------------------------------------------------------------
__device__ __forceinline__ float pairwise512_sq(const float* __restrict__ p) {
    float blk[4];
#pragma unroll
    for (int b = 0; b < 4; ++b) {
        const float* a = p + b * 128;
        float r[8];
#pragma unroll
        for (int j = 0; j < 8; ++j) r[j] = __fmul_rn(a[j], a[j]);
#pragma unroll
        for (int i = 8; i < 128; i += 8) {
#pragma unroll
            for (int j = 0; j < 8; ++j)
                r[j] = __fadd_rn(r[j], __fmul_rn(a[i + j], a[i + j]));
        }
        blk[b] = __fadd_rn(__fadd_rn(__fadd_rn(r[0], r[1]), __fadd_rn(r[2], r[3])),
                           __fadd_rn(__fadd_rn(r[4], r[5]), __fadd_rn(r[6], r[7])));
    }
    return __fadd_rn(__fadd_rn(blk[0], blk[1]), __fadd_rn(blk[2], blk[3]));
}

__global__ void ee_kernel(const float* __restrict__ E, float* __restrict__ ee) {
    int k = blockIdx.x * blockDim.x + threadIdx.x;
    if (k < KCB) ee[k] = pairwise512_sq(E + (size_t)k * DIM);
}

__global__ __launch_bounds__(512, 2)
void argmin_fallback(const float* __restrict__ Z, const float* __restrict__ E,
                     const float* __restrict__ ee, int* __restrict__ outIdx) {
    __shared__ __align__(16) char smem[(32 * 132 + 32 * 260) * 4];
    float (*As)[132] = (float (*)[132])smem;
    float (*Bs)[260] = (float (*)[260])(smem + 32 * 132 * 4);
    __shared__ float zzs[128];
    const int tid = threadIdx.x;
    const int tx = tid & 31;
    const int ty = tid >> 5;
    const int rowBase = blockIdx.x * 128;
    if (tid < 128) zzs[tid] = pairwise512_sq(Z + (size_t)(rowBase + tid) * DIM);
    __syncthreads();
    float zz[8];
#pragma unroll
    for (int m = 0; m < 8; ++m) zz[m] = zzs[ty * 8 + m];
    float bestV[8]; int bestI[8];
#pragma unroll
    for (int m = 0; m < 8; ++m) { bestV[m] = __builtin_inff(); bestI[m] = 0; }
    for (int tile = 0; tile < 32; ++tile) {
        float acc[8][8];
#pragma unroll
        for (int m = 0; m < 8; ++m)
#pragma unroll
            for (int n = 0; n < 8; ++n) acc[m][n] = 0.0f;
        for (int kc = 0; kc < DIM; kc += 32) {
            __syncthreads();
#pragma unroll
            for (int i = 0; i < 2; ++i) {
                int id4 = tid + i * 512;
                int r = id4 >> 3, c = id4 & 7;
                float4 v = *(const float4*)(Z + (size_t)(rowBase + r) * DIM + kc + c * 4);
                As[c * 4 + 0][r] = v.x; As[c * 4 + 1][r] = v.y;
                As[c * 4 + 2][r] = v.z; As[c * 4 + 3][r] = v.w;
            }
#pragma unroll
            for (int i = 0; i < 4; ++i) {
                int id4 = tid + i * 512;
                int r = id4 >> 3, c = id4 & 7;
                float4 v = *(const float4*)(E + (size_t)(tile * 256 + r) * DIM + kc + c * 4);
                Bs[c * 4 + 0][r] = v.x; Bs[c * 4 + 1][r] = v.y;
                Bs[c * 4 + 2][r] = v.z; Bs[c * 4 + 3][r] = v.w;
            }
            __syncthreads();
#pragma unroll
            for (int kk = 0; kk < 32; ++kk) {
                float a[8], b[8];
                *(float4*)&a[0] = *(const float4*)&As[kk][ty * 8];
                *(float4*)&a[4] = *(const float4*)&As[kk][ty * 8 + 4];
                *(float4*)&b[0] = *(const float4*)&Bs[kk][tx * 8];
                *(float4*)&b[4] = *(const float4*)&Bs[kk][tx * 8 + 4];
#pragma unroll
                for (int m = 0; m < 8; ++m)
#pragma unroll
                    for (int n = 0; n < 8; ++n)
                        acc[m][n] = __builtin_fmaf(a[m], b[n], acc[m][n]);
            }
        }
#pragma unroll
        for (int m = 0; m < 8; ++m) {
#pragma unroll
            for (int n = 0; n < 8; ++n) {
                float t = __builtin_fmaf(-2.0f, acc[m][n], zz[m]);
                float d2 = __fadd_rn(t, ee[tile * 256 + tx * 8 + n]);
                int kidx = tile * 256 + tx * 8 + n;
                if (d2 < bestV[m]) { bestV[m] = d2; bestI[m] = kidx; }
            }
        }
    }
    __syncthreads();
    float (*redV)[33] = (float (*)[33])smem;
    int   (*redI)[33] = (int (*)[33])(smem + 128 * 33 * 4);
#pragma unroll
    for (int m = 0; m < 8; ++m) {
        redV[ty * 8 + m][tx] = bestV[m];
        redI[ty * 8 + m][tx] = bestI[m];
    }
    __syncthreads();
    if (tid < 128) {
        float bv = redV[tid][0]; int bi = redI[tid][0];
        for (int j = 1; j < 32; ++j) {
            float v = redV[tid][j]; int ii = redI[tid][j];
            if (v < bv || (v == bv && ii < bi)) { bv = v; bi = ii; }
        }
        outIdx[rowBase + tid] = bi;
    }
}

__global__ void gather_kernel(const float* __restrict__ Z, const float* __restrict__ E,
                              const int* __restrict__ idx, float* __restrict__ outZ,
                              float* __restrict__ outIdxF, double* __restrict__ lossAcc) {
    int row = blockIdx.x;
    int t = threadIdx.x;  // 64
    int k = idx[row];
    const float* zr = Z + (size_t)row * DIM;
    const float* er = E + (size_t)k * DIM;
    float* orow = outZ + (size_t)row * DIM;
    double s = 0.0;
#pragma unroll
    for (int i = 0; i < 2; ++i) {
        int off = (t + i * 64) * 4;
        float4 z4 = *(const float4*)(zr + off);
        float4 e4 = *(const float4*)(er + off);
        float dx = __fsub_rn(e4.x, z4.x);
        float dy = __fsub_rn(e4.y, z4.y);
        float dz = __fsub_rn(e4.z, z4.z);
        float dw = __fsub_rn(e4.w, z4.w);
        float4 st;
        st.x = __fadd_rn(z4.x, dx);
        st.y = __fadd_rn(z4.y, dy);
        st.z = __fadd_rn(z4.z, dz);
        st.w = __fadd_rn(z4.w, dw);
        *(float4*)(orow + off) = st;
        s += (double)dx * dx + (double)dy * dy + (double)dz * dz + (double)dw * dw;
    }
#pragma unroll
    for (int o = 32; o > 0; o >>= 1) s += __shfl_down(s, o, 64);
    if (t == 0) {
        atomicAdd(lossAcc, s);
        outIdxF[row] = (float)k;
    }
}

// ---------------------------------------------------------------------------
extern "C" void kernel_launch(void* const* d_in, const int* in_sizes, int n_in,
                              void* d_out, int out_size, void* d_ws, size_t ws_size,
                              hipStream_t stream) {
    const float* Z = (const float*)d_in[0];
    const float* E = (const float*)d_in[1];
    float* out = (float*)d_out;
    float* zq_out = out;
    float* loss_out = out + (size_t)NROWS * DIM;
    float* idxf_out = loss_out + 1;

    if (ws_size >= WS_NEEDED_64) {
        const int cap = (ws_size >= WS_NEEDED_128) ? 128 : 64;
        _Float16* Zh = (_Float16*)((char*)d_ws + OFF_ZH);
        _Float16* Eh = (_Float16*)((char*)d_ws + OFF_EH);
        float* ee = (float*)((char*)d_ws + OFF_EE);
        float* zz = (float*)((char*)d_ws + OFF_ZZ);
        unsigned int* cnt = (unsigned int*)((char*)d_ws + OFF_CNT);
        unsigned int* cand = (unsigned int*)((char*)d_ws + OFF_CAND);
        unsigned int* rowmax = (unsigned int*)((char*)d_ws + OFF_CAND
                                               + (size_t)NROWS * cap * 4);
        double* lossAcc = (double*)((char*)d_ws + OFF_LOSS);

        prep2_kernel<<<(NROWS + KCB) * 4 / 256, 256, 0, stream>>>(Z, E, Zh, Eh, zz, ee,
                                                                  cnt, rowmax, lossAcc);
        screen_kernel<<<256 * 64, 256, 0, stream>>>(Zh, Eh, cnt, cand, rowmax, cap);
        finish_kernel<<<NROWS / 8, 256, 0, stream>>>(Z, E, zz, ee, cnt, cand,
                                                     zq_out, idxf_out, lossAcc, cap);
        finalize_kernel<<<1, 1, 0, stream>>>(lossAcc, loss_out);
    } else {
        float* ee = (float*)d_ws;
        int* idx = (int*)((char*)d_ws + 32768);
        double* lossAcc = (double*)((char*)d_ws + 163840);
        hipMemsetAsync(lossAcc, 0, sizeof(double), stream);
        ee_kernel<<<KCB / 256, 256, 0, stream>>>(E, ee);
        argmin_fallback<<<NROWS / 128, 512, 0, stream>>>(Z, E, ee, idx);
        gather_kernel<<<NROWS, 64, 0, stream>>>(Z, E, idx, zq_out, idxf_out, lossAcc);
        finalize_kernel<<<1, 1, 0, stream>>>(lossAcc, loss_out);
    }
}